// Round 17
// baseline (116.756 us; speedup 1.0000x reference)
//
#include <hip/hip_runtime.h>

typedef short bf16x8 __attribute__((ext_vector_type(8)));
typedef float f32x4 __attribute__((ext_vector_type(4)));
typedef unsigned short u16;
typedef unsigned short u16x8 __attribute__((ext_vector_type(8)));
typedef float f32x4_a __attribute__((ext_vector_type(4), may_alias));

__device__ __forceinline__ u16 f2bf(float f) {
    union { float f; unsigned u; } v; v.f = f;
    unsigned r = v.u + 0x7fffu + ((v.u >> 16) & 1u);
    return (u16)(r >> 16);
}
// cheap round-half-up (for P: normalization cancels the tiny bias)
__device__ __forceinline__ u16 f2bf_rhu(float f) {
    union { float f; unsigned u; } v; v.f = f;
    return (u16)((v.u + 0x8000u) >> 16);
}

// async global->LDS, 16B per lane. lds base must be wave-uniform (HW adds lane*16).
__device__ __forceinline__ void gld_lds16(const void* g, void* l) {
    __builtin_amdgcn_global_load_lds(
        (const __attribute__((address_space(1))) void*)g,
        (__attribute__((address_space(3))) void*)l, 16, 0, 0);
}

// ---------------------------------------------------------------------------
// Fused prep: x fp32->bf16 (blocks 0..2047), w_qkv transpose+cvt (2048..5119).
// (w_proj transpose moved into the attn launch -- overlaps the attn tail.)
// ---------------------------------------------------------------------------
__global__ __launch_bounds__(256) void prep_kernel(
    const float* __restrict__ x, u16* __restrict__ xb,
    const float* __restrict__ w_qkv, u16* __restrict__ wqkvT) {
    __shared__ float tile[32][33];
    const int b = blockIdx.x, tid = threadIdx.x;
    if (b < 2048) {
        const int i = b * 256 + tid;
        float4 a = ((const float4*)x)[i * 2];
        float4 c = ((const float4*)x)[i * 2 + 1];
        u16x8 h;
        h[0] = f2bf(a.x); h[1] = f2bf(a.y); h[2] = f2bf(a.z); h[3] = f2bf(a.w);
        h[4] = f2bf(c.x); h[5] = f2bf(c.y); h[6] = f2bf(c.z); h[7] = f2bf(c.w);
        *(u16x8*)(xb + (size_t)i * 8) = h;
        return;
    }
    const int bx = b - 2048;           // 3072 tiles: N=3072
    const int n0 = (bx % 96) * 32, k0 = (bx / 96) * 32;
    const int tx = tid & 31, ty = tid >> 5;
#pragma unroll
    for (int i = 0; i < 32; i += 8)
        tile[ty + i][tx] = w_qkv[(size_t)(k0 + ty + i) * 3072 + n0 + tx];
    __syncthreads();
#pragma unroll
    for (int i = 0; i < 32; i += 8)
        wqkvT[(size_t)(n0 + ty + i) * 1024 + k0 + tx] = f2bf(tile[tx][ty + i]);
}

// ---------------------------------------------------------------------------
// GEMM: C[M,N] = A[M,K](bf16) * Bt[N,K]^T + bias
// BM=128, BN in {128,64}. 4 waves (2x2), BK=64, global_load_lds x16 staging
// with both-sides XOR swizzle (frag reads 2-way = free), 16 K-steps.
// OUTMODE 0: scatter Q (pre-scaled by 0.125*log2e) / K as [B,H,T,D],
//            V transposed as [B,H,D,T].  OUTMODE 1: fp32 C + bias.
// ---------------------------------------------------------------------------
#define QSCALE 0.180336880f  // 0.125 * log2(e)

template <int OUTMODE, int BN>
__global__ __launch_bounds__(256) void gemm_m97(
    const u16* __restrict__ A, const u16* __restrict__ Bt,
    const float* __restrict__ bias, float* __restrict__ Cf,
    u16* __restrict__ Qo, u16* __restrict__ Ko, u16* __restrict__ Vt,
    int M, int N, int K) {
    constexpr int NF = BN / 32;  // n-frags per wave (wave covers BN/2 cols)
    __shared__ __align__(16) u16 lA[128 * 64];
    __shared__ __align__(16) u16 lB[BN * 64];

    const int tid = threadIdx.x;
    const int lane = tid & 63, wid = tid >> 6;
    const int wr = wid >> 1, wc = wid & 1;
    const int fr = lane & 15, fq = lane >> 4;
    const int m0 = blockIdx.y * 128, n0 = blockIdx.x * BN;

    const int gsrc = (lane & 7) ^ (lane >> 3);
    const u16* gA0 = A + (size_t)(m0 + (tid >> 3)) * K + gsrc * 8;
    const u16* gB0 = Bt + (size_t)(n0 + (tid >> 3)) * K + gsrc * 8;
    u16* lAw = lA + wid * 512;
    u16* lBw = lB + wid * 512;

    const int r7 = fr & 7;
    const int gk[2] = { ((0 + fq) ^ r7) * 8, ((4 + fq) ^ r7) * 8 };

    f32x4 acc[4][NF];
#pragma unroll
    for (int m = 0; m < 4; m++)
#pragma unroll
        for (int n = 0; n < NF; n++)
#pragma unroll
            for (int r = 0; r < 4; r++) acc[m][n][r] = 0.f;

    for (int k0 = 0; k0 < K; k0 += 64) {
        __syncthreads();
#pragma unroll
        for (int c = 0; c < 4; c++)
            gld_lds16(gA0 + (size_t)(c * 32) * K + k0, lAw + c * 2048);
#pragma unroll
        for (int c = 0; c < BN / 32; c++)
            gld_lds16(gB0 + (size_t)(c * 32) * K + k0, lBw + c * 2048);
        __syncthreads();

#pragma unroll
        for (int kf = 0; kf < 2; kf++) {
            bf16x8 a[4], b[NF];
#pragma unroll
            for (int m = 0; m < 4; m++)
                a[m] = *(const bf16x8*)&lA[(wr * 64 + m * 16 + fr) * 64 + gk[kf]];
#pragma unroll
            for (int n = 0; n < NF; n++)
                b[n] = *(const bf16x8*)&lB[(wc * (BN / 2) + n * 16 + fr) * 64 + gk[kf]];
#pragma unroll
            for (int m = 0; m < 4; m++)
#pragma unroll
                for (int n = 0; n < NF; n++)
                    acc[m][n] = __builtin_amdgcn_mfma_f32_16x16x32_bf16(a[m], b[n], acc[m][n], 0, 0, 0);
        }
    }

#pragma unroll
    for (int m = 0; m < 4; m++) {
#pragma unroll
        for (int n = 0; n < NF; n++) {
            const int row0 = m0 + wr * 64 + m * 16 + fq * 4;
            const int col = n0 + wc * (BN / 2) + n * 16 + fr;
            float v4[4];
#pragma unroll
            for (int r = 0; r < 4; r++) v4[r] = acc[m][n][r] + bias[col];
            if (OUTMODE == 0) {
                const int bb = row0 >> 11, t0 = row0 & 2047;
                const int sec = col >> 10, cc = col & 1023;
                const int h = cc >> 6, d = cc & 63;
                if (sec == 0) {
#pragma unroll
                    for (int r = 0; r < 4; r++)
                        Qo[(((size_t)(bb * 16 + h) * 2048 + t0 + r) << 6) + d] = f2bf(v4[r] * QSCALE);
                } else if (sec == 1) {
#pragma unroll
                    for (int r = 0; r < 4; r++)
                        Ko[(((size_t)(bb * 16 + h) * 2048 + t0 + r) << 6) + d] = f2bf(v4[r]);
                } else {
                    ushort4 p;
                    p.x = f2bf(v4[0]); p.y = f2bf(v4[1]); p.z = f2bf(v4[2]); p.w = f2bf(v4[3]);
                    *(ushort4*)&Vt[(((size_t)(bb * 16 + h) * 64 + d) << 11) + t0] = p;
                }
            } else {
#pragma unroll
                for (int r = 0; r < 4; r++)
                    Cf[(size_t)(row0 + r) * N + col] = v4[r];
            }
        }
    }
}

// ---------------------------------------------------------------------------
// Causal flash attention (R16 structure) + IN-REGISTER P via permlane swaps.
// P never touches LDS: after S^T, each lane packs its 4 k-consecutive P pairs
// into u32s (a=w[0][0], b=w[0][1], c=w[1][0], d=w[1][1]) and two
// v_permlane32_swap + v_permlane16_swap pairs redistribute them into the PV
// B-fragment (VALU pipe, not DS). Derivation (quadrants over fq):
//   pl32(a,c): a=[a0 a1 c0 c1], c=[a2 a3 c2 c3]
//   pl16(a,c): a=[a0 a2 c0 c2]=e0, c=[a1 a3 c1 c3]=e2   (same for b,d -> e1,e3)
// giving lane (fq,fr) elem j = P[k=fq*8+j][q=fr], the exact B-frag layout.
// Removes 6 DS ops / 16 KB per block-tile (-25% of the binding LDS traffic)
// and the P write->read dependency. LDS 24 KB -> 6 blocks/CU.
// Blocks >= 1024 do the w_proj transpose (moved out of prep; overlaps tail).
// Q,K bf16 [BH,T,64]; Vt bf16 [BH,64,T]; O bf16 [B,T,H*64].
// ---------------------------------------------------------------------------
__global__ __launch_bounds__(256, 5) void attn_kernel(const u16* __restrict__ Q,
                                                      const u16* __restrict__ Kg,
                                                      const u16* __restrict__ Vt,
                                                      u16* __restrict__ O,
                                                      const float* __restrict__ wp,
                                                      u16* __restrict__ wpT) {
    // unified 24 KB: lK dbuf [2][64*64] + lV [64*64]; the f32 combine scratch
    // (20 KB) and the transpose tile (4.2 KB) overlay it.
    __shared__ __align__(16) u16 smem[12288];

    const int tid = threadIdx.x;

    if (blockIdx.x >= 1024) {  // ---- w_proj transpose tile (from prep) ----
        float* tile = (float*)smem;  // [32][33]
        const int bx = blockIdx.x - 1024;
        const int n0 = (bx & 31) * 32, k0 = (bx >> 5) * 32;
        const int tx = tid & 31, ty = tid >> 5;
#pragma unroll
        for (int i = 0; i < 32; i += 8)
            tile[(ty + i) * 33 + tx] = wp[(size_t)(k0 + ty + i) * 1024 + n0 + tx];
        __syncthreads();
#pragma unroll
        for (int i = 0; i < 32; i += 8)
            wpT[(size_t)(n0 + ty + i) * 1024 + k0 + tx] = f2bf(tile[tx * 33 + ty + i]);
        return;
    }

    u16* lV = smem + 8192;
    const int lane = tid & 63, wid = tid >> 6;
    const int fr = lane & 15, fq = lane >> 4;
    const int kw = wid >> 1, qw = wid & 1;  // k-half / q-half roles
    const int bh = blockIdx.x & 31;
    const int qi = 31 - (blockIdx.x >> 5);  // heavy blocks first
    const int qb0 = qi * 64;
    const size_t base = (size_t)bh * (2048 * 64);
    const u16* Qp = Q + base;
    const u16* Kp = Kg + base;
    const u16* Vp = Vt + base;  // [64][2048]

    const int q0w = qb0 + qw * 32;
    bf16x8 qa[2][2];  // [qg][kf]
#pragma unroll
    for (int qg = 0; qg < 2; qg++)
#pragma unroll
        for (int kf = 0; kf < 2; kf++)
            qa[qg][kf] = *(const bf16x8*)&Qp[(size_t)(q0w + qg * 16 + fr) * 64 + kf * 32 + fq * 8];
    // (qa loads drain at the prologue vmcnt(0) below)

    bf16x8 vones;
#pragma unroll
    for (int j = 0; j < 8; j++) vones[j] = (short)0x3F80;  // bf16 1.0

    f32x4 o[4][2], lsum[2];  // [dg][qg] / [qg]
#pragma unroll
    for (int qg = 0; qg < 2; qg++) {
#pragma unroll
        for (int r = 0; r < 4; r++) lsum[qg][r] = 0.f;
#pragma unroll
        for (int dg = 0; dg < 4; dg++)
#pragma unroll
            for (int r = 0; r < 4; r++) o[dg][qg][r] = 0.f;
    }

    // --- staging geometry (both-sides swizzle, rule #21) ---
    const int srow0 = wid * 8 + (lane >> 3);
    const int gsrc = (lane & 7) ^ (lane >> 3);
    const u16* kSrc0 = Kp + (size_t)srow0 * 64 + gsrc * 8;
    const u16* vSrc0 = Vp + ((size_t)srow0 << 11) + gsrc * 8;

    // --- fragment read granules (same XOR on read) ---
    const int r7 = fr & 7;
    const int gk0 = ((0 + fq) ^ r7) * 8;        // K d-granule, kf=0
    const int gk1 = ((4 + fq) ^ r7) * 8;        // K d-granule, kf=1
    const int gkv = ((kw * 4 + fq) ^ r7) * 8;   // V k-granule for this k-half

    const int nt = qi + 1;

#define STAGE_K(bufofs, kt0_)                                                   \
    do {                                                                        \
        u16* _lkw = smem + (bufofs) + wid * 512;                                \
        gld_lds16(kSrc0 + (size_t)(kt0_) * 64, _lkw);                           \
        gld_lds16(kSrc0 + (size_t)((kt0_) + 32) * 64, _lkw + 2048);             \
    } while (0)
#define STAGE_V(kt0_)                                                           \
    do {                                                                        \
        u16* _lvw = lV + wid * 512;                                             \
        gld_lds16(vSrc0 + (kt0_), _lvw);                                        \
        gld_lds16(vSrc0 + ((size_t)32 << 11) + (kt0_), _lvw + 2048);            \
    } while (0)

    // prologue: K(0)+V(0), drain all (incl. qa), publish
    STAGE_K(0, 0);
    STAGE_V(0);
    asm volatile("s_waitcnt vmcnt(0)" ::: "memory");
    __builtin_amdgcn_s_barrier();

    for (int kt = 0; kt < nt; kt++) {
        const int kt0 = kt << 6;
        const int curofs = (kt & 1) ? 4096 : 0;

        if (kt + 1 < nt) {
            STAGE_K(curofs ^ 4096, kt0 + 64);
            asm volatile("s_waitcnt vmcnt(2)" ::: "memory");  // K(kt),V(kt) landed
            __builtin_amdgcn_s_barrier();
        } else if (nt > 1) {
            asm volatile("s_waitcnt vmcnt(0)" ::: "memory");  // last tile drains
            __builtin_amdgcn_s_barrier();
        }
        const u16* lKc = smem + curofs;

        // S^T[k32][q32] = K_half Q_half^T   (exp2 domain; Q pre-scaled)
        f32x4 s[2][2];  // [kg][qg]
#pragma unroll
        for (int kg = 0; kg < 2; kg++)
#pragma unroll
            for (int qg = 0; qg < 2; qg++)
#pragma unroll
                for (int r = 0; r < 4; r++) s[kg][qg][r] = 0.f;
        __builtin_amdgcn_s_setprio(1);
#pragma unroll
        for (int kg = 0; kg < 2; kg++) {
            const int krow = (kw * 32 + kg * 16 + fr) * 64;
            bf16x8 kb0 = *(const bf16x8*)&lKc[krow + gk0];
            bf16x8 kb1 = *(const bf16x8*)&lKc[krow + gk1];
#pragma unroll
            for (int qg = 0; qg < 2; qg++) {
                s[kg][qg] = __builtin_amdgcn_mfma_f32_16x16x32_bf16(kb0, qa[qg][0], s[kg][qg], 0, 0, 0);
                s[kg][qg] = __builtin_amdgcn_mfma_f32_16x16x32_bf16(kb1, qa[qg][1], s[kg][qg], 0, 0, 0);
            }
        }
        __builtin_amdgcn_s_setprio(0);

        if (kt == nt - 1) {  // only the diagonal tile can cross the boundary
#pragma unroll
            for (int kg = 0; kg < 2; kg++) {
                const int kg0 = kt0 + kw * 32 + kg * 16 + fq * 4;
#pragma unroll
                for (int qg = 0; qg < 2; qg++) {
                    const int qg0 = q0w + qg * 16 + fr;
#pragma unroll
                    for (int r = 0; r < 4; r++)
                        if (kg0 + r > qg0) s[kg][qg][r] = -200.f;  // exp2 -> 0
                }
            }
        }

        // V frags (LDS) for PV
        bf16x8 va[4];
#pragma unroll
        for (int dg = 0; dg < 4; dg++)
            va[dg] = *(const bf16x8*)&lV[(dg * 16 + fr) * 64 + gkv];

        // P = exp2(S) -> in-register B-frag via permlane swaps (no LDS)
#pragma unroll
        for (int qg = 0; qg < 2; qg++) {
            unsigned pa = (unsigned)f2bf_rhu(__builtin_amdgcn_exp2f(s[0][qg][0])) |
                          ((unsigned)f2bf_rhu(__builtin_amdgcn_exp2f(s[0][qg][1])) << 16);
            unsigned pb_ = (unsigned)f2bf_rhu(__builtin_amdgcn_exp2f(s[0][qg][2])) |
                           ((unsigned)f2bf_rhu(__builtin_amdgcn_exp2f(s[0][qg][3])) << 16);
            unsigned pc = (unsigned)f2bf_rhu(__builtin_amdgcn_exp2f(s[1][qg][0])) |
                          ((unsigned)f2bf_rhu(__builtin_amdgcn_exp2f(s[1][qg][1])) << 16);
            unsigned pd = (unsigned)f2bf_rhu(__builtin_amdgcn_exp2f(s[1][qg][2])) |
                          ((unsigned)f2bf_rhu(__builtin_amdgcn_exp2f(s[1][qg][3])) << 16);
            asm("v_permlane32_swap_b32 %0, %1" : "+v"(pa), "+v"(pc));
            asm("v_permlane16_swap_b32 %0, %1" : "+v"(pa), "+v"(pc));
            asm("v_permlane32_swap_b32 %0, %1" : "+v"(pb_), "+v"(pd));
            asm("v_permlane16_swap_b32 %0, %1" : "+v"(pb_), "+v"(pd));
            union { unsigned u[4]; bf16x8 v; } pbu;
            pbu.u[0] = pa; pbu.u[1] = pb_; pbu.u[2] = pc; pbu.u[3] = pd;
            const bf16x8 pb = pbu.v;

            __builtin_amdgcn_s_setprio(1);
            lsum[qg] = __builtin_amdgcn_mfma_f32_16x16x32_bf16(vones, pb, lsum[qg], 0, 0, 0);
#pragma unroll
            for (int dg = 0; dg < 4; dg++)
                o[dg][qg] = __builtin_amdgcn_mfma_f32_16x16x32_bf16(va[dg], pb, o[dg][qg], 0, 0, 0);
            __builtin_amdgcn_s_setprio(0);
        }

        if (kt + 1 < nt) {
            __builtin_amdgcn_s_barrier();  // all waves done reading lV / lK[cur]
            STAGE_V(kt0 + 64);             // safe to overwrite lV now
        }
    }
#undef STAGE_K
#undef STAGE_V

    // all waves done with lK/lV before the overlay writes
    __syncthreads();

    // ---- combine k-halves over the (dead) smem: 2 x 64 lanes x 40 f32 ----
    float* cmb = (float*)smem;
    float* slab = cmb + (size_t)qw * 2560 + lane * 40;
    if (kw == 1) {
#pragma unroll
        for (int dg = 0; dg < 4; dg++)
#pragma unroll
            for (int qg = 0; qg < 2; qg++)
                *(f32x4_a*)&slab[(dg * 2 + qg) * 4] = o[dg][qg];
#pragma unroll
        for (int qg = 0; qg < 2; qg++)
            *(f32x4_a*)&slab[32 + qg * 4] = lsum[qg];
    }
    __syncthreads();
    if (kw == 0) {
#pragma unroll
        for (int dg = 0; dg < 4; dg++)
#pragma unroll
            for (int qg = 0; qg < 2; qg++) {
                f32x4_a p = *(const f32x4_a*)&slab[(dg * 2 + qg) * 4];
#pragma unroll
                for (int r = 0; r < 4; r++) o[dg][qg][r] += p[r];
            }
#pragma unroll
        for (int qg = 0; qg < 2; qg++) {
            f32x4_a p = *(const f32x4_a*)&slab[32 + qg * 4];
            lsum[qg][0] += p[0];
        }

        // epilogue: lane holds O^T[d=dg*16+fq*4+r][q=q0w+qg*16+fr]
        const int bb = bh >> 4, hh = bh & 15;
#pragma unroll
        for (int qg = 0; qg < 2; qg++) {
            const float inv = 1.f / lsum[qg][0];
            u16* orow = O + ((size_t)(bb * 2048 + q0w + qg * 16 + fr)) * 1024 + hh * 64 + fq * 4;
#pragma unroll
            for (int dg = 0; dg < 4; dg++) {
                ushort4 h;
                h.x = f2bf(o[dg][qg][0] * inv);
                h.y = f2bf(o[dg][qg][1] * inv);
                h.z = f2bf(o[dg][qg][2] * inv);
                h.w = f2bf(o[dg][qg][3] * inv);
                *(ushort4*)&orow[dg * 16] = h;
            }
        }
    }
}

// ---------------------------------------------------------------------------
extern "C" void kernel_launch(void* const* d_in, const int* in_sizes, int n_in,
                              void* d_out, int out_size, void* d_ws, size_t ws_size,
                              hipStream_t stream) {
    const float* x      = (const float*)d_in[0];
    const float* w_qkv  = (const float*)d_in[1];
    const float* b_qkv  = (const float*)d_in[2];
    const float* w_proj = (const float*)d_in[3];
    const float* b_proj = (const float*)d_in[4];
    float* out = (float*)d_out;

    u16* ws = (u16*)d_ws;
    u16* wqkvT  = ws;                      // 3072*1024
    u16* wprojT = wqkvT + 3072 * 1024;     // 1024*1024
    u16* Qb     = wprojT + 1024 * 1024;    // 32*2048*64
    u16* Kb     = Qb + 32 * 2048 * 64;
    u16* Vtb    = Kb + 32 * 2048 * 64;     // transposed V [BH,64,2048]
    u16* xb     = Vtb + 32 * 2048 * 64;    // x as bf16; reused as attnO
    u16* attnO  = xb;                      // alias (xb dead after gemm1)

    prep_kernel<<<5120, 256, 0, stream>>>(x, xb, w_qkv, wqkvT);

    gemm_m97<0, 128><<<dim3(24, 32), 256, 0, stream>>>(
        xb, wqkvT, b_qkv, nullptr, Qb, Kb, Vtb, 4096, 3072, 1024);

    attn_kernel<<<2048, 256, 0, stream>>>(Qb, Kb, Vtb, attnO, w_proj, wprojT);

    gemm_m97<1, 64><<<dim3(16, 32), 256, 0, stream>>>(
        attnO, wprojT, b_proj, out, nullptr, nullptr, nullptr, 4096, 1024, 1024);
}

// Round 18
// 94.306 us; speedup vs baseline: 1.2381x; 1.2381x over previous
//
#include <hip/hip_runtime.h>

typedef short bf16x8 __attribute__((ext_vector_type(8)));
typedef float f32x4 __attribute__((ext_vector_type(4)));
typedef unsigned short u16;
typedef unsigned short u16x8 __attribute__((ext_vector_type(8)));
typedef float f32x4_a __attribute__((ext_vector_type(4), may_alias));

__device__ __forceinline__ u16 f2bf(float f) {
    union { float f; unsigned u; } v; v.f = f;
    unsigned r = v.u + 0x7fffu + ((v.u >> 16) & 1u);
    return (u16)(r >> 16);
}
// cheap round-half-up (for P: normalization cancels the tiny bias)
__device__ __forceinline__ u16 f2bf_rhu(float f) {
    union { float f; unsigned u; } v; v.f = f;
    return (u16)((v.u + 0x8000u) >> 16);
}

// async global->LDS, 16B per lane. lds base must be wave-uniform (HW adds lane*16).
__device__ __forceinline__ void gld_lds16(const void* g, void* l) {
    __builtin_amdgcn_global_load_lds(
        (const __attribute__((address_space(1))) void*)g,
        (__attribute__((address_space(3))) void*)l, 16, 0, 0);
}

// ---------------------------------------------------------------------------
// Fused prep: x fp32->bf16 (blocks 0..2047), w_qkv transpose+cvt (2048..5119).
// (w_proj transpose rides in the attn launch -- overlaps the attn tail.)
// ---------------------------------------------------------------------------
__global__ __launch_bounds__(256) void prep_kernel(
    const float* __restrict__ x, u16* __restrict__ xb,
    const float* __restrict__ w_qkv, u16* __restrict__ wqkvT) {
    __shared__ float tile[32][33];
    const int b = blockIdx.x, tid = threadIdx.x;
    if (b < 2048) {
        const int i = b * 256 + tid;
        float4 a = ((const float4*)x)[i * 2];
        float4 c = ((const float4*)x)[i * 2 + 1];
        u16x8 h;
        h[0] = f2bf(a.x); h[1] = f2bf(a.y); h[2] = f2bf(a.z); h[3] = f2bf(a.w);
        h[4] = f2bf(c.x); h[5] = f2bf(c.y); h[6] = f2bf(c.z); h[7] = f2bf(c.w);
        *(u16x8*)(xb + (size_t)i * 8) = h;
        return;
    }
    const int bx = b - 2048;           // 3072 tiles: N=3072
    const int n0 = (bx % 96) * 32, k0 = (bx / 96) * 32;
    const int tx = tid & 31, ty = tid >> 5;
#pragma unroll
    for (int i = 0; i < 32; i += 8)
        tile[ty + i][tx] = w_qkv[(size_t)(k0 + ty + i) * 3072 + n0 + tx];
    __syncthreads();
#pragma unroll
    for (int i = 0; i < 32; i += 8)
        wqkvT[(size_t)(n0 + ty + i) * 1024 + k0 + tx] = f2bf(tile[tx][ty + i]);
}

// ---------------------------------------------------------------------------
// GEMM: C[M,N] = A[M,K](bf16) * Bt[N,K]^T + bias
// BM=128, BN in {128,64}. 4 waves (2x2), BK=64, global_load_lds x16 staging
// with both-sides XOR swizzle (frag reads 2-way = free), 16 K-steps.
// OUTMODE 0: scatter Q (pre-scaled by 0.125*log2e) / K as [B,H,T,D],
//            V transposed as [B,H,D,T].  OUTMODE 1: fp32 C + bias.
// ---------------------------------------------------------------------------
#define QSCALE 0.180336880f  // 0.125 * log2(e)

template <int OUTMODE, int BN>
__global__ __launch_bounds__(256) void gemm_m97(
    const u16* __restrict__ A, const u16* __restrict__ Bt,
    const float* __restrict__ bias, float* __restrict__ Cf,
    u16* __restrict__ Qo, u16* __restrict__ Ko, u16* __restrict__ Vt,
    int M, int N, int K) {
    constexpr int NF = BN / 32;  // n-frags per wave (wave covers BN/2 cols)
    __shared__ __align__(16) u16 lA[128 * 64];
    __shared__ __align__(16) u16 lB[BN * 64];

    const int tid = threadIdx.x;
    const int lane = tid & 63, wid = tid >> 6;
    const int wr = wid >> 1, wc = wid & 1;
    const int fr = lane & 15, fq = lane >> 4;
    const int m0 = blockIdx.y * 128, n0 = blockIdx.x * BN;

    const int gsrc = (lane & 7) ^ (lane >> 3);
    const u16* gA0 = A + (size_t)(m0 + (tid >> 3)) * K + gsrc * 8;
    const u16* gB0 = Bt + (size_t)(n0 + (tid >> 3)) * K + gsrc * 8;
    u16* lAw = lA + wid * 512;
    u16* lBw = lB + wid * 512;

    const int r7 = fr & 7;
    const int gk[2] = { ((0 + fq) ^ r7) * 8, ((4 + fq) ^ r7) * 8 };

    f32x4 acc[4][NF];
#pragma unroll
    for (int m = 0; m < 4; m++)
#pragma unroll
        for (int n = 0; n < NF; n++)
#pragma unroll
            for (int r = 0; r < 4; r++) acc[m][n][r] = 0.f;

    for (int k0 = 0; k0 < K; k0 += 64) {
        __syncthreads();
#pragma unroll
        for (int c = 0; c < 4; c++)
            gld_lds16(gA0 + (size_t)(c * 32) * K + k0, lAw + c * 2048);
#pragma unroll
        for (int c = 0; c < BN / 32; c++)
            gld_lds16(gB0 + (size_t)(c * 32) * K + k0, lBw + c * 2048);
        __syncthreads();

#pragma unroll
        for (int kf = 0; kf < 2; kf++) {
            bf16x8 a[4], b[NF];
#pragma unroll
            for (int m = 0; m < 4; m++)
                a[m] = *(const bf16x8*)&lA[(wr * 64 + m * 16 + fr) * 64 + gk[kf]];
#pragma unroll
            for (int n = 0; n < NF; n++)
                b[n] = *(const bf16x8*)&lB[(wc * (BN / 2) + n * 16 + fr) * 64 + gk[kf]];
#pragma unroll
            for (int m = 0; m < 4; m++)
#pragma unroll
                for (int n = 0; n < NF; n++)
                    acc[m][n] = __builtin_amdgcn_mfma_f32_16x16x32_bf16(a[m], b[n], acc[m][n], 0, 0, 0);
        }
    }

#pragma unroll
    for (int m = 0; m < 4; m++) {
#pragma unroll
        for (int n = 0; n < NF; n++) {
            const int row0 = m0 + wr * 64 + m * 16 + fq * 4;
            const int col = n0 + wc * (BN / 2) + n * 16 + fr;
            float v4[4];
#pragma unroll
            for (int r = 0; r < 4; r++) v4[r] = acc[m][n][r] + bias[col];
            if (OUTMODE == 0) {
                const int bb = row0 >> 11, t0 = row0 & 2047;
                const int sec = col >> 10, cc = col & 1023;
                const int h = cc >> 6, d = cc & 63;
                if (sec == 0) {
#pragma unroll
                    for (int r = 0; r < 4; r++)
                        Qo[(((size_t)(bb * 16 + h) * 2048 + t0 + r) << 6) + d] = f2bf(v4[r] * QSCALE);
                } else if (sec == 1) {
#pragma unroll
                    for (int r = 0; r < 4; r++)
                        Ko[(((size_t)(bb * 16 + h) * 2048 + t0 + r) << 6) + d] = f2bf(v4[r]);
                } else {
                    ushort4 p;
                    p.x = f2bf(v4[0]); p.y = f2bf(v4[1]); p.z = f2bf(v4[2]); p.w = f2bf(v4[3]);
                    *(ushort4*)&Vt[(((size_t)(bb * 16 + h) * 64 + d) << 11) + t0] = p;
                }
            } else {
#pragma unroll
                for (int r = 0; r < 4; r++)
                    Cf[(size_t)(row0 + r) * N + col] = v4[r];
            }
        }
    }
}

// ---------------------------------------------------------------------------
// Causal flash attention: R17 structure (in-register P via permlane swaps)
// with the launch-bounds fix. R17's regression was __launch_bounds__(256,5):
// VGPR capped at 48 -> live set (~110) spilled to scratch (FETCH_SIZE
// 12.3->28.4 MB). (256,4) caps at 128 -> no spill; permlane-P's wins stand
// (bank conflicts 540K->245K, LDS 24 KB, no P write->read DS dependency).
// Blocks >= 1024 do the w_proj transpose (overlaps the attn tail).
// Q,K bf16 [BH,T,64]; Vt bf16 [BH,64,T]; O bf16 [B,T,H*64].
// ---------------------------------------------------------------------------
__global__ __launch_bounds__(256, 4) void attn_kernel(const u16* __restrict__ Q,
                                                      const u16* __restrict__ Kg,
                                                      const u16* __restrict__ Vt,
                                                      u16* __restrict__ O,
                                                      const float* __restrict__ wp,
                                                      u16* __restrict__ wpT) {
    // unified 24 KB: lK dbuf [2][64*64] + lV [64*64]; the f32 combine scratch
    // (20 KB) and the transpose tile (4.2 KB) overlay it.
    __shared__ __align__(16) u16 smem[12288];

    const int tid = threadIdx.x;

    if (blockIdx.x >= 1024) {  // ---- w_proj transpose tile (from prep) ----
        float* tile = (float*)smem;  // [32][33]
        const int bx = blockIdx.x - 1024;
        const int n0 = (bx & 31) * 32, k0 = (bx >> 5) * 32;
        const int tx = tid & 31, ty = tid >> 5;
#pragma unroll
        for (int i = 0; i < 32; i += 8)
            tile[(ty + i) * 33 + tx] = wp[(size_t)(k0 + ty + i) * 1024 + n0 + tx];
        __syncthreads();
#pragma unroll
        for (int i = 0; i < 32; i += 8)
            wpT[(size_t)(n0 + ty + i) * 1024 + k0 + tx] = f2bf(tile[tx * 33 + ty + i]);
        return;
    }

    u16* lV = smem + 8192;
    const int lane = tid & 63, wid = tid >> 6;
    const int fr = lane & 15, fq = lane >> 4;
    const int kw = wid >> 1, qw = wid & 1;  // k-half / q-half roles
    const int bh = blockIdx.x & 31;
    const int qi = 31 - (blockIdx.x >> 5);  // heavy blocks first
    const int qb0 = qi * 64;
    const size_t base = (size_t)bh * (2048 * 64);
    const u16* Qp = Q + base;
    const u16* Kp = Kg + base;
    const u16* Vp = Vt + base;  // [64][2048]

    const int q0w = qb0 + qw * 32;
    bf16x8 qa[2][2];  // [qg][kf]
#pragma unroll
    for (int qg = 0; qg < 2; qg++)
#pragma unroll
        for (int kf = 0; kf < 2; kf++)
            qa[qg][kf] = *(const bf16x8*)&Qp[(size_t)(q0w + qg * 16 + fr) * 64 + kf * 32 + fq * 8];
    // (qa loads drain at the prologue vmcnt(0) below)

    bf16x8 vones;
#pragma unroll
    for (int j = 0; j < 8; j++) vones[j] = (short)0x3F80;  // bf16 1.0

    f32x4 o[4][2], lsum[2];  // [dg][qg] / [qg]
#pragma unroll
    for (int qg = 0; qg < 2; qg++) {
#pragma unroll
        for (int r = 0; r < 4; r++) lsum[qg][r] = 0.f;
#pragma unroll
        for (int dg = 0; dg < 4; dg++)
#pragma unroll
            for (int r = 0; r < 4; r++) o[dg][qg][r] = 0.f;
    }

    // --- staging geometry (both-sides swizzle, rule #21) ---
    const int srow0 = wid * 8 + (lane >> 3);
    const int gsrc = (lane & 7) ^ (lane >> 3);
    const u16* kSrc0 = Kp + (size_t)srow0 * 64 + gsrc * 8;
    const u16* vSrc0 = Vp + ((size_t)srow0 << 11) + gsrc * 8;

    // --- fragment read granules (same XOR on read) ---
    const int r7 = fr & 7;
    const int gk0 = ((0 + fq) ^ r7) * 8;        // K d-granule, kf=0
    const int gk1 = ((4 + fq) ^ r7) * 8;        // K d-granule, kf=1
    const int gkv = ((kw * 4 + fq) ^ r7) * 8;   // V k-granule for this k-half

    const int nt = qi + 1;

#define STAGE_K(bufofs, kt0_)                                                   \
    do {                                                                        \
        u16* _lkw = smem + (bufofs) + wid * 512;                                \
        gld_lds16(kSrc0 + (size_t)(kt0_) * 64, _lkw);                           \
        gld_lds16(kSrc0 + (size_t)((kt0_) + 32) * 64, _lkw + 2048);             \
    } while (0)
#define STAGE_V(kt0_)                                                           \
    do {                                                                        \
        u16* _lvw = lV + wid * 512;                                             \
        gld_lds16(vSrc0 + (kt0_), _lvw);                                        \
        gld_lds16(vSrc0 + ((size_t)32 << 11) + (kt0_), _lvw + 2048);            \
    } while (0)

    // prologue: K(0)+V(0), drain all (incl. qa), publish
    STAGE_K(0, 0);
    STAGE_V(0);
    asm volatile("s_waitcnt vmcnt(0)" ::: "memory");
    __builtin_amdgcn_s_barrier();

    for (int kt = 0; kt < nt; kt++) {
        const int kt0 = kt << 6;
        const int curofs = (kt & 1) ? 4096 : 0;

        if (kt + 1 < nt) {
            STAGE_K(curofs ^ 4096, kt0 + 64);
            asm volatile("s_waitcnt vmcnt(2)" ::: "memory");  // K(kt),V(kt) landed
            __builtin_amdgcn_s_barrier();
        } else if (nt > 1) {
            asm volatile("s_waitcnt vmcnt(0)" ::: "memory");  // last tile drains
            __builtin_amdgcn_s_barrier();
        }
        const u16* lKc = smem + curofs;

        // S^T[k32][q32] = K_half Q_half^T   (exp2 domain; Q pre-scaled)
        f32x4 s[2][2];  // [kg][qg]
#pragma unroll
        for (int kg = 0; kg < 2; kg++)
#pragma unroll
            for (int qg = 0; qg < 2; qg++)
#pragma unroll
                for (int r = 0; r < 4; r++) s[kg][qg][r] = 0.f;
        __builtin_amdgcn_s_setprio(1);
#pragma unroll
        for (int kg = 0; kg < 2; kg++) {
            const int krow = (kw * 32 + kg * 16 + fr) * 64;
            bf16x8 kb0 = *(const bf16x8*)&lKc[krow + gk0];
            bf16x8 kb1 = *(const bf16x8*)&lKc[krow + gk1];
#pragma unroll
            for (int qg = 0; qg < 2; qg++) {
                s[kg][qg] = __builtin_amdgcn_mfma_f32_16x16x32_bf16(kb0, qa[qg][0], s[kg][qg], 0, 0, 0);
                s[kg][qg] = __builtin_amdgcn_mfma_f32_16x16x32_bf16(kb1, qa[qg][1], s[kg][qg], 0, 0, 0);
            }
        }
        __builtin_amdgcn_s_setprio(0);

        if (kt == nt - 1) {  // only the diagonal tile can cross the boundary
#pragma unroll
            for (int kg = 0; kg < 2; kg++) {
                const int kg0 = kt0 + kw * 32 + kg * 16 + fq * 4;
#pragma unroll
                for (int qg = 0; qg < 2; qg++) {
                    const int qg0 = q0w + qg * 16 + fr;
#pragma unroll
                    for (int r = 0; r < 4; r++)
                        if (kg0 + r > qg0) s[kg][qg][r] = -200.f;  // exp2 -> 0
                }
            }
        }

        // V frags (LDS) for PV
        bf16x8 va[4];
#pragma unroll
        for (int dg = 0; dg < 4; dg++)
            va[dg] = *(const bf16x8*)&lV[(dg * 16 + fr) * 64 + gkv];

        // P = exp2(S) -> in-register B-frag via permlane swaps (no LDS)
#pragma unroll
        for (int qg = 0; qg < 2; qg++) {
            unsigned pa = (unsigned)f2bf_rhu(__builtin_amdgcn_exp2f(s[0][qg][0])) |
                          ((unsigned)f2bf_rhu(__builtin_amdgcn_exp2f(s[0][qg][1])) << 16);
            unsigned pb_ = (unsigned)f2bf_rhu(__builtin_amdgcn_exp2f(s[0][qg][2])) |
                           ((unsigned)f2bf_rhu(__builtin_amdgcn_exp2f(s[0][qg][3])) << 16);
            unsigned pc = (unsigned)f2bf_rhu(__builtin_amdgcn_exp2f(s[1][qg][0])) |
                          ((unsigned)f2bf_rhu(__builtin_amdgcn_exp2f(s[1][qg][1])) << 16);
            unsigned pd = (unsigned)f2bf_rhu(__builtin_amdgcn_exp2f(s[1][qg][2])) |
                          ((unsigned)f2bf_rhu(__builtin_amdgcn_exp2f(s[1][qg][3])) << 16);
            asm("v_permlane32_swap_b32 %0, %1" : "+v"(pa), "+v"(pc));
            asm("v_permlane16_swap_b32 %0, %1" : "+v"(pa), "+v"(pc));
            asm("v_permlane32_swap_b32 %0, %1" : "+v"(pb_), "+v"(pd));
            asm("v_permlane16_swap_b32 %0, %1" : "+v"(pb_), "+v"(pd));
            union { unsigned u[4]; bf16x8 v; } pbu;
            pbu.u[0] = pa; pbu.u[1] = pb_; pbu.u[2] = pc; pbu.u[3] = pd;
            const bf16x8 pb = pbu.v;

            __builtin_amdgcn_s_setprio(1);
            lsum[qg] = __builtin_amdgcn_mfma_f32_16x16x32_bf16(vones, pb, lsum[qg], 0, 0, 0);
#pragma unroll
            for (int dg = 0; dg < 4; dg++)
                o[dg][qg] = __builtin_amdgcn_mfma_f32_16x16x32_bf16(va[dg], pb, o[dg][qg], 0, 0, 0);
            __builtin_amdgcn_s_setprio(0);
        }

        if (kt + 1 < nt) {
            __builtin_amdgcn_s_barrier();  // all waves done reading lV / lK[cur]
            STAGE_V(kt0 + 64);             // safe to overwrite lV now
        }
    }
#undef STAGE_K
#undef STAGE_V

    // all waves done with lK/lV before the overlay writes
    __syncthreads();

    // ---- combine k-halves over the (dead) smem: 2 x 64 lanes x 40 f32 ----
    float* cmb = (float*)smem;
    float* slab = cmb + (size_t)qw * 2560 + lane * 40;
    if (kw == 1) {
#pragma unroll
        for (int dg = 0; dg < 4; dg++)
#pragma unroll
            for (int qg = 0; qg < 2; qg++)
                *(f32x4_a*)&slab[(dg * 2 + qg) * 4] = o[dg][qg];
#pragma unroll
        for (int qg = 0; qg < 2; qg++)
            *(f32x4_a*)&slab[32 + qg * 4] = lsum[qg];
    }
    __syncthreads();
    if (kw == 0) {
#pragma unroll
        for (int dg = 0; dg < 4; dg++)
#pragma unroll
            for (int qg = 0; qg < 2; qg++) {
                f32x4_a p = *(const f32x4_a*)&slab[(dg * 2 + qg) * 4];
#pragma unroll
                for (int r = 0; r < 4; r++) o[dg][qg][r] += p[r];
            }
#pragma unroll
        for (int qg = 0; qg < 2; qg++) {
            f32x4_a p = *(const f32x4_a*)&slab[32 + qg * 4];
            lsum[qg][0] += p[0];
        }

        // epilogue: lane holds O^T[d=dg*16+fq*4+r][q=q0w+qg*16+fr]
        const int bb = bh >> 4, hh = bh & 15;
#pragma unroll
        for (int qg = 0; qg < 2; qg++) {
            const float inv = 1.f / lsum[qg][0];
            u16* orow = O + ((size_t)(bb * 2048 + q0w + qg * 16 + fr)) * 1024 + hh * 64 + fq * 4;
#pragma unroll
            for (int dg = 0; dg < 4; dg++) {
                ushort4 h;
                h.x = f2bf(o[dg][qg][0] * inv);
                h.y = f2bf(o[dg][qg][1] * inv);
                h.z = f2bf(o[dg][qg][2] * inv);
                h.w = f2bf(o[dg][qg][3] * inv);
                *(ushort4*)&orow[dg * 16] = h;
            }
        }
    }
}

// ---------------------------------------------------------------------------
extern "C" void kernel_launch(void* const* d_in, const int* in_sizes, int n_in,
                              void* d_out, int out_size, void* d_ws, size_t ws_size,
                              hipStream_t stream) {
    const float* x      = (const float*)d_in[0];
    const float* w_qkv  = (const float*)d_in[1];
    const float* b_qkv  = (const float*)d_in[2];
    const float* w_proj = (const float*)d_in[3];
    const float* b_proj = (const float*)d_in[4];
    float* out = (float*)d_out;

    u16* ws = (u16*)d_ws;
    u16* wqkvT  = ws;                      // 3072*1024
    u16* wprojT = wqkvT + 3072 * 1024;     // 1024*1024
    u16* Qb     = wprojT + 1024 * 1024;    // 32*2048*64
    u16* Kb     = Qb + 32 * 2048 * 64;
    u16* Vtb    = Kb + 32 * 2048 * 64;     // transposed V [BH,64,2048]
    u16* xb     = Vtb + 32 * 2048 * 64;    // x as bf16; reused as attnO
    u16* attnO  = xb;                      // alias (xb dead after gemm1)

    prep_kernel<<<5120, 256, 0, stream>>>(x, xb, w_qkv, wqkvT);

    gemm_m97<0, 128><<<dim3(24, 32), 256, 0, stream>>>(
        xb, wqkvT, b_qkv, nullptr, Qb, Kb, Vtb, 4096, 3072, 1024);

    attn_kernel<<<2048, 256, 0, stream>>>(Qb, Kb, Vtb, attnO, w_proj, wprojT);

    gemm_m97<1, 64><<<dim3(16, 32), 256, 0, stream>>>(
        attnO, wprojT, b_proj, out, nullptr, nullptr, nullptr, 4096, 1024, 1024);
}

// Round 19
// 91.679 us; speedup vs baseline: 1.2735x; 1.0287x over previous
//
#include <hip/hip_runtime.h>

typedef short bf16x8 __attribute__((ext_vector_type(8)));
typedef float f32x4 __attribute__((ext_vector_type(4)));
typedef unsigned short u16;
typedef unsigned short u16x8 __attribute__((ext_vector_type(8)));
typedef float f32x4_a __attribute__((ext_vector_type(4), may_alias));

__device__ __forceinline__ u16 f2bf(float f) {
    union { float f; unsigned u; } v; v.f = f;
    unsigned r = v.u + 0x7fffu + ((v.u >> 16) & 1u);
    return (u16)(r >> 16);
}
// cheap round-half-up (for P: normalization cancels the tiny bias)
__device__ __forceinline__ u16 f2bf_rhu(float f) {
    union { float f; unsigned u; } v; v.f = f;
    return (u16)((v.u + 0x8000u) >> 16);
}

// async global->LDS, 16B per lane. lds base must be wave-uniform (HW adds lane*16).
__device__ __forceinline__ void gld_lds16(const void* g, void* l) {
    __builtin_amdgcn_global_load_lds(
        (const __attribute__((address_space(1))) void*)g,
        (__attribute__((address_space(3))) void*)l, 16, 0, 0);
}

// ---------------------------------------------------------------------------
// Fused prep: x fp32->bf16 (blocks 0..2047), w_qkv transpose+cvt (2048..5119).
// (w_proj transpose rides in the attn launch -- overlaps the attn tail.)
// ---------------------------------------------------------------------------
__global__ __launch_bounds__(256) void prep_kernel(
    const float* __restrict__ x, u16* __restrict__ xb,
    const float* __restrict__ w_qkv, u16* __restrict__ wqkvT) {
    __shared__ float tile[32][33];
    const int b = blockIdx.x, tid = threadIdx.x;
    if (b < 2048) {
        const int i = b * 256 + tid;
        float4 a = ((const float4*)x)[i * 2];
        float4 c = ((const float4*)x)[i * 2 + 1];
        u16x8 h;
        h[0] = f2bf(a.x); h[1] = f2bf(a.y); h[2] = f2bf(a.z); h[3] = f2bf(a.w);
        h[4] = f2bf(c.x); h[5] = f2bf(c.y); h[6] = f2bf(c.z); h[7] = f2bf(c.w);
        *(u16x8*)(xb + (size_t)i * 8) = h;
        return;
    }
    const int bx = b - 2048;           // 3072 tiles: N=3072
    const int n0 = (bx % 96) * 32, k0 = (bx / 96) * 32;
    const int tx = tid & 31, ty = tid >> 5;
#pragma unroll
    for (int i = 0; i < 32; i += 8)
        tile[ty + i][tx] = w_qkv[(size_t)(k0 + ty + i) * 3072 + n0 + tx];
    __syncthreads();
#pragma unroll
    for (int i = 0; i < 32; i += 8)
        wqkvT[(size_t)(n0 + ty + i) * 1024 + k0 + tx] = f2bf(tile[tx][ty + i]);
}

#define QSCALE 0.180336880f  // 0.125 * log2(e)

// ---------------------------------------------------------------------------
// gemm1, 8-wave 4-phase (T3/T4/T5): C = xb[4096,1024] * wqkvT[3072,1024]^T.
// BM=256, BN=192 -> grid 16x16 = 256 blocks = 1/CU (full coverage).
// BK=64, dbuf LDS 112 KB (1 block/CU). Per K-tile: issue ALL next-tile DMA
// up front (loads span the whole tile's compute), then 4 phases
// {ds-read subtile -> setprio MFMA cluster -> barrier}; one vmcnt(0)/tile.
// A-half register subtile cached across 2 phases, B-frags across 3.
// Epilogue scatters Q (pre-scaled), K as [B,H,T,D]; V transposed [B,H,D,T].
// ---------------------------------------------------------------------------
__global__ __launch_bounds__(512, 2) void gemm_8ph(
    const u16* __restrict__ A, const u16* __restrict__ Bt,
    const float* __restrict__ bias,
    u16* __restrict__ Qo, u16* __restrict__ Ko, u16* __restrict__ Vt) {
    const int K = 1024;
    // lA[2][256*64] @ 0, 16384 ; lB[2][192*64] @ 32768, 45056  (u16 units)
    __shared__ __align__(16) u16 smem[57344];  // 112 KB

    const int tid = threadIdx.x;
    const int lane = tid & 63, wid = tid >> 6;
    const int wm = wid >> 2, wn = wid & 3;     // 2 x 4 wave grid
    const int fr = lane & 15, fq = lane >> 4;
    const int m0 = blockIdx.y * 256, n0 = blockIdx.x * 192;

    // staging: call c covers rows c*64 + (tid>>3); source granule pre-swizzled
    const int gsrc = (tid & 7) ^ ((tid >> 3) & 7);
    const u16* gA0 = A + (size_t)(m0 + (tid >> 3)) * K + gsrc * 8;
    const u16* gB0 = Bt + (size_t)(n0 + (tid >> 3)) * K + gsrc * 8;

    // fragment read granules (same XOR on read)
    const int r7 = fr & 7;
    const int gk0 = ((0 + fq) ^ r7) * 8;
    const int gk1 = ((4 + fq) ^ r7) * 8;

    f32x4 acc[8][3];
#pragma unroll
    for (int m = 0; m < 8; m++)
#pragma unroll
        for (int n = 0; n < 3; n++)
#pragma unroll
            for (int r = 0; r < 4; r++) acc[m][n][r] = 0.f;

#define STAGE8(t)                                                               \
    do {                                                                        \
        const int _b = (t) & 1;                                                 \
        const size_t _ko = (size_t)(t) * 64;                                    \
        u16* _la = smem + _b * 16384 + wid * 512;                               \
        u16* _lb = smem + 32768 + _b * 12288 + wid * 512;                       \
        gld_lds16(gA0 + _ko, _la);                                              \
        gld_lds16(gA0 + (size_t)64 * 1024 + _ko, _la + 4096);                   \
        gld_lds16(gA0 + (size_t)128 * 1024 + _ko, _la + 8192);                  \
        gld_lds16(gA0 + (size_t)192 * 1024 + _ko, _la + 12288);                 \
        gld_lds16(gB0 + _ko, _lb);                                              \
        gld_lds16(gB0 + (size_t)64 * 1024 + _ko, _lb + 4096);                   \
        gld_lds16(gB0 + (size_t)128 * 1024 + _ko, _lb + 8192);                  \
    } while (0)

    STAGE8(0);
    asm volatile("s_waitcnt vmcnt(0)" ::: "memory");
    __builtin_amdgcn_s_barrier();

    for (int t = 0; t < 16; t++) {
        const int b = t & 1;
        const u16* lA = smem + b * 16384;
        const u16* lB = smem + 32768 + b * 12288;
        if (t + 1 < 16) STAGE8(t + 1);  // rides over this tile's 4 phases

        bf16x8 aR[4][2], b01[2][2], b2[2];

        // ---- phase A: mh=0, nf 0-1 ----
#pragma unroll
        for (int mf = 0; mf < 4; mf++) {
            const int row = (wm * 128 + mf * 16 + fr) * 64;
            aR[mf][0] = *(const bf16x8*)&lA[row + gk0];
            aR[mf][1] = *(const bf16x8*)&lA[row + gk1];
        }
#pragma unroll
        for (int nf = 0; nf < 2; nf++) {
            const int row = (wn * 48 + nf * 16 + fr) * 64;
            b01[nf][0] = *(const bf16x8*)&lB[row + gk0];
            b01[nf][1] = *(const bf16x8*)&lB[row + gk1];
        }
        __builtin_amdgcn_s_setprio(1);
#pragma unroll
        for (int mf = 0; mf < 4; mf++)
#pragma unroll
            for (int nf = 0; nf < 2; nf++) {
                acc[mf][nf] = __builtin_amdgcn_mfma_f32_16x16x32_bf16(aR[mf][0], b01[nf][0], acc[mf][nf], 0, 0, 0);
                acc[mf][nf] = __builtin_amdgcn_mfma_f32_16x16x32_bf16(aR[mf][1], b01[nf][1], acc[mf][nf], 0, 0, 0);
            }
        __builtin_amdgcn_s_setprio(0);
        __builtin_amdgcn_s_barrier();

        // ---- phase B: mh=0, nf 2 ----
        {
            const int row = (wn * 48 + 32 + fr) * 64;
            b2[0] = *(const bf16x8*)&lB[row + gk0];
            b2[1] = *(const bf16x8*)&lB[row + gk1];
        }
        __builtin_amdgcn_s_setprio(1);
#pragma unroll
        for (int mf = 0; mf < 4; mf++) {
            acc[mf][2] = __builtin_amdgcn_mfma_f32_16x16x32_bf16(aR[mf][0], b2[0], acc[mf][2], 0, 0, 0);
            acc[mf][2] = __builtin_amdgcn_mfma_f32_16x16x32_bf16(aR[mf][1], b2[1], acc[mf][2], 0, 0, 0);
        }
        __builtin_amdgcn_s_setprio(0);
        __builtin_amdgcn_s_barrier();

        // ---- phase C: mh=1, nf 2 ----
#pragma unroll
        for (int mf = 0; mf < 4; mf++) {
            const int row = (wm * 128 + 64 + mf * 16 + fr) * 64;
            aR[mf][0] = *(const bf16x8*)&lA[row + gk0];
            aR[mf][1] = *(const bf16x8*)&lA[row + gk1];
        }
        __builtin_amdgcn_s_setprio(1);
#pragma unroll
        for (int mf = 0; mf < 4; mf++) {
            acc[4 + mf][2] = __builtin_amdgcn_mfma_f32_16x16x32_bf16(aR[mf][0], b2[0], acc[4 + mf][2], 0, 0, 0);
            acc[4 + mf][2] = __builtin_amdgcn_mfma_f32_16x16x32_bf16(aR[mf][1], b2[1], acc[4 + mf][2], 0, 0, 0);
        }
        __builtin_amdgcn_s_setprio(0);
        __builtin_amdgcn_s_barrier();

        // ---- phase D: mh=1, nf 0-1 (b01 still live) ----
        __builtin_amdgcn_s_setprio(1);
#pragma unroll
        for (int mf = 0; mf < 4; mf++)
#pragma unroll
            for (int nf = 0; nf < 2; nf++) {
                acc[4 + mf][nf] = __builtin_amdgcn_mfma_f32_16x16x32_bf16(aR[mf][0], b01[nf][0], acc[4 + mf][nf], 0, 0, 0);
                acc[4 + mf][nf] = __builtin_amdgcn_mfma_f32_16x16x32_bf16(aR[mf][1], b01[nf][1], acc[4 + mf][nf], 0, 0, 0);
            }
        __builtin_amdgcn_s_setprio(0);

        // next tile landed + all waves done with buf b
        asm volatile("s_waitcnt vmcnt(0)" ::: "memory");
        __builtin_amdgcn_s_barrier();
    }
#undef STAGE8

    // epilogue: scatter Q/K/V
#pragma unroll
    for (int mf = 0; mf < 8; mf++) {
#pragma unroll
        for (int nf = 0; nf < 3; nf++) {
            const int row0 = m0 + wm * 128 + mf * 16 + fq * 4;
            const int col = n0 + wn * 48 + nf * 16 + fr;
            float v4[4];
#pragma unroll
            for (int r = 0; r < 4; r++) v4[r] = acc[mf][nf][r] + bias[col];
            const int bb = row0 >> 11, t0 = row0 & 2047;
            const int sec = col >> 10, cc = col & 1023;
            const int h = cc >> 6, d = cc & 63;
            if (sec == 0) {
#pragma unroll
                for (int r = 0; r < 4; r++)
                    Qo[(((size_t)(bb * 16 + h) * 2048 + t0 + r) << 6) + d] = f2bf(v4[r] * QSCALE);
            } else if (sec == 1) {
#pragma unroll
                for (int r = 0; r < 4; r++)
                    Ko[(((size_t)(bb * 16 + h) * 2048 + t0 + r) << 6) + d] = f2bf(v4[r]);
            } else {
                ushort4 p;
                p.x = f2bf(v4[0]); p.y = f2bf(v4[1]); p.z = f2bf(v4[2]); p.w = f2bf(v4[3]);
                *(ushort4*)&Vt[(((size_t)(bb * 16 + h) * 64 + d) << 11) + t0] = p;
            }
        }
    }
}

// ---------------------------------------------------------------------------
// GEMM (m97-family) kept for gemm3: C[M,N] = A[M,K](bf16) * Bt[N,K]^T + bias.
// BM=128, BN=64. 4 waves, BK=64, gld_lds staging + both-sides XOR swizzle.
// ---------------------------------------------------------------------------
template <int BN>
__global__ __launch_bounds__(256) void gemm_m97(
    const u16* __restrict__ A, const u16* __restrict__ Bt,
    const float* __restrict__ bias, float* __restrict__ Cf,
    int M, int N, int K) {
    constexpr int NF = BN / 32;
    __shared__ __align__(16) u16 lA[128 * 64];
    __shared__ __align__(16) u16 lB[BN * 64];

    const int tid = threadIdx.x;
    const int lane = tid & 63, wid = tid >> 6;
    const int wr = wid >> 1, wc = wid & 1;
    const int fr = lane & 15, fq = lane >> 4;
    const int m0 = blockIdx.y * 128, n0 = blockIdx.x * BN;

    const int gsrc = (lane & 7) ^ (lane >> 3);
    const u16* gA0 = A + (size_t)(m0 + (tid >> 3)) * K + gsrc * 8;
    const u16* gB0 = Bt + (size_t)(n0 + (tid >> 3)) * K + gsrc * 8;
    u16* lAw = lA + wid * 512;
    u16* lBw = lB + wid * 512;

    const int r7 = fr & 7;
    const int gk[2] = { ((0 + fq) ^ r7) * 8, ((4 + fq) ^ r7) * 8 };

    f32x4 acc[4][NF];
#pragma unroll
    for (int m = 0; m < 4; m++)
#pragma unroll
        for (int n = 0; n < NF; n++)
#pragma unroll
            for (int r = 0; r < 4; r++) acc[m][n][r] = 0.f;

    for (int k0 = 0; k0 < K; k0 += 64) {
        __syncthreads();
#pragma unroll
        for (int c = 0; c < 4; c++)
            gld_lds16(gA0 + (size_t)(c * 32) * K + k0, lAw + c * 2048);
#pragma unroll
        for (int c = 0; c < BN / 32; c++)
            gld_lds16(gB0 + (size_t)(c * 32) * K + k0, lBw + c * 2048);
        __syncthreads();

#pragma unroll
        for (int kf = 0; kf < 2; kf++) {
            bf16x8 a[4], b[NF];
#pragma unroll
            for (int m = 0; m < 4; m++)
                a[m] = *(const bf16x8*)&lA[(wr * 64 + m * 16 + fr) * 64 + gk[kf]];
#pragma unroll
            for (int n = 0; n < NF; n++)
                b[n] = *(const bf16x8*)&lB[(wc * (BN / 2) + n * 16 + fr) * 64 + gk[kf]];
#pragma unroll
            for (int m = 0; m < 4; m++)
#pragma unroll
                for (int n = 0; n < NF; n++)
                    acc[m][n] = __builtin_amdgcn_mfma_f32_16x16x32_bf16(a[m], b[n], acc[m][n], 0, 0, 0);
        }
    }

#pragma unroll
    for (int m = 0; m < 4; m++) {
#pragma unroll
        for (int n = 0; n < NF; n++) {
            const int row0 = m0 + wr * 64 + m * 16 + fq * 4;
            const int col = n0 + wc * (BN / 2) + n * 16 + fr;
#pragma unroll
            for (int r = 0; r < 4; r++)
                Cf[(size_t)(row0 + r) * N + col] = acc[m][n][r] + bias[col];
        }
    }
}

// ---------------------------------------------------------------------------
// Causal flash attention (R18 structure, unchanged): swapped-operand, 2x2 wave
// role split, in-register P via permlane swaps, single-buffered V, 24 KB LDS.
// Blocks >= 1024 do the w_proj transpose (overlaps the attn tail).
// ---------------------------------------------------------------------------
__global__ __launch_bounds__(256, 4) void attn_kernel(const u16* __restrict__ Q,
                                                      const u16* __restrict__ Kg,
                                                      const u16* __restrict__ Vt,
                                                      u16* __restrict__ O,
                                                      const float* __restrict__ wp,
                                                      u16* __restrict__ wpT) {
    __shared__ __align__(16) u16 smem[12288];

    const int tid = threadIdx.x;

    if (blockIdx.x >= 1024) {  // ---- w_proj transpose tile ----
        float* tile = (float*)smem;  // [32][33]
        const int bx = blockIdx.x - 1024;
        const int n0 = (bx & 31) * 32, k0 = (bx >> 5) * 32;
        const int tx = tid & 31, ty = tid >> 5;
#pragma unroll
        for (int i = 0; i < 32; i += 8)
            tile[(ty + i) * 33 + tx] = wp[(size_t)(k0 + ty + i) * 1024 + n0 + tx];
        __syncthreads();
#pragma unroll
        for (int i = 0; i < 32; i += 8)
            wpT[(size_t)(n0 + ty + i) * 1024 + k0 + tx] = f2bf(tile[tx * 33 + ty + i]);
        return;
    }

    u16* lV = smem + 8192;
    const int lane = tid & 63, wid = tid >> 6;
    const int fr = lane & 15, fq = lane >> 4;
    const int kw = wid >> 1, qw = wid & 1;
    const int bh = blockIdx.x & 31;
    const int qi = 31 - (blockIdx.x >> 5);
    const int qb0 = qi * 64;
    const size_t base = (size_t)bh * (2048 * 64);
    const u16* Qp = Q + base;
    const u16* Kp = Kg + base;
    const u16* Vp = Vt + base;

    const int q0w = qb0 + qw * 32;
    bf16x8 qa[2][2];
#pragma unroll
    for (int qg = 0; qg < 2; qg++)
#pragma unroll
        for (int kf = 0; kf < 2; kf++)
            qa[qg][kf] = *(const bf16x8*)&Qp[(size_t)(q0w + qg * 16 + fr) * 64 + kf * 32 + fq * 8];

    bf16x8 vones;
#pragma unroll
    for (int j = 0; j < 8; j++) vones[j] = (short)0x3F80;

    f32x4 o[4][2], lsum[2];
#pragma unroll
    for (int qg = 0; qg < 2; qg++) {
#pragma unroll
        for (int r = 0; r < 4; r++) lsum[qg][r] = 0.f;
#pragma unroll
        for (int dg = 0; dg < 4; dg++)
#pragma unroll
            for (int r = 0; r < 4; r++) o[dg][qg][r] = 0.f;
    }

    const int srow0 = wid * 8 + (lane >> 3);
    const int gsrc = (lane & 7) ^ (lane >> 3);
    const u16* kSrc0 = Kp + (size_t)srow0 * 64 + gsrc * 8;
    const u16* vSrc0 = Vp + ((size_t)srow0 << 11) + gsrc * 8;

    const int r7 = fr & 7;
    const int gk0 = ((0 + fq) ^ r7) * 8;
    const int gk1 = ((4 + fq) ^ r7) * 8;
    const int gkv = ((kw * 4 + fq) ^ r7) * 8;

    const int nt = qi + 1;

#define STAGE_K(bufofs, kt0_)                                                   \
    do {                                                                        \
        u16* _lkw = smem + (bufofs) + wid * 512;                                \
        gld_lds16(kSrc0 + (size_t)(kt0_) * 64, _lkw);                           \
        gld_lds16(kSrc0 + (size_t)((kt0_) + 32) * 64, _lkw + 2048);             \
    } while (0)
#define STAGE_V(kt0_)                                                           \
    do {                                                                        \
        u16* _lvw = lV + wid * 512;                                             \
        gld_lds16(vSrc0 + (kt0_), _lvw);                                        \
        gld_lds16(vSrc0 + ((size_t)32 << 11) + (kt0_), _lvw + 2048);            \
    } while (0)

    STAGE_K(0, 0);
    STAGE_V(0);
    asm volatile("s_waitcnt vmcnt(0)" ::: "memory");
    __builtin_amdgcn_s_barrier();

    for (int kt = 0; kt < nt; kt++) {
        const int kt0 = kt << 6;
        const int curofs = (kt & 1) ? 4096 : 0;

        if (kt + 1 < nt) {
            STAGE_K(curofs ^ 4096, kt0 + 64);
            asm volatile("s_waitcnt vmcnt(2)" ::: "memory");
            __builtin_amdgcn_s_barrier();
        } else if (nt > 1) {
            asm volatile("s_waitcnt vmcnt(0)" ::: "memory");
            __builtin_amdgcn_s_barrier();
        }
        const u16* lKc = smem + curofs;

        f32x4 s[2][2];
#pragma unroll
        for (int kg = 0; kg < 2; kg++)
#pragma unroll
            for (int qg = 0; qg < 2; qg++)
#pragma unroll
                for (int r = 0; r < 4; r++) s[kg][qg][r] = 0.f;
        __builtin_amdgcn_s_setprio(1);
#pragma unroll
        for (int kg = 0; kg < 2; kg++) {
            const int krow = (kw * 32 + kg * 16 + fr) * 64;
            bf16x8 kb0 = *(const bf16x8*)&lKc[krow + gk0];
            bf16x8 kb1 = *(const bf16x8*)&lKc[krow + gk1];
#pragma unroll
            for (int qg = 0; qg < 2; qg++) {
                s[kg][qg] = __builtin_amdgcn_mfma_f32_16x16x32_bf16(kb0, qa[qg][0], s[kg][qg], 0, 0, 0);
                s[kg][qg] = __builtin_amdgcn_mfma_f32_16x16x32_bf16(kb1, qa[qg][1], s[kg][qg], 0, 0, 0);
            }
        }
        __builtin_amdgcn_s_setprio(0);

        if (kt == nt - 1) {
#pragma unroll
            for (int kg = 0; kg < 2; kg++) {
                const int kg0 = kt0 + kw * 32 + kg * 16 + fq * 4;
#pragma unroll
                for (int qg = 0; qg < 2; qg++) {
                    const int qg0 = q0w + qg * 16 + fr;
#pragma unroll
                    for (int r = 0; r < 4; r++)
                        if (kg0 + r > qg0) s[kg][qg][r] = -200.f;
                }
            }
        }

        bf16x8 va[4];
#pragma unroll
        for (int dg = 0; dg < 4; dg++)
            va[dg] = *(const bf16x8*)&lV[(dg * 16 + fr) * 64 + gkv];

#pragma unroll
        for (int qg = 0; qg < 2; qg++) {
            unsigned pa = (unsigned)f2bf_rhu(__builtin_amdgcn_exp2f(s[0][qg][0])) |
                          ((unsigned)f2bf_rhu(__builtin_amdgcn_exp2f(s[0][qg][1])) << 16);
            unsigned pb_ = (unsigned)f2bf_rhu(__builtin_amdgcn_exp2f(s[0][qg][2])) |
                           ((unsigned)f2bf_rhu(__builtin_amdgcn_exp2f(s[0][qg][3])) << 16);
            unsigned pc = (unsigned)f2bf_rhu(__builtin_amdgcn_exp2f(s[1][qg][0])) |
                          ((unsigned)f2bf_rhu(__builtin_amdgcn_exp2f(s[1][qg][1])) << 16);
            unsigned pd = (unsigned)f2bf_rhu(__builtin_amdgcn_exp2f(s[1][qg][2])) |
                          ((unsigned)f2bf_rhu(__builtin_amdgcn_exp2f(s[1][qg][3])) << 16);
            asm("v_permlane32_swap_b32 %0, %1" : "+v"(pa), "+v"(pc));
            asm("v_permlane16_swap_b32 %0, %1" : "+v"(pa), "+v"(pc));
            asm("v_permlane32_swap_b32 %0, %1" : "+v"(pb_), "+v"(pd));
            asm("v_permlane16_swap_b32 %0, %1" : "+v"(pb_), "+v"(pd));
            union { unsigned u[4]; bf16x8 v; } pbu;
            pbu.u[0] = pa; pbu.u[1] = pb_; pbu.u[2] = pc; pbu.u[3] = pd;
            const bf16x8 pb = pbu.v;

            __builtin_amdgcn_s_setprio(1);
            lsum[qg] = __builtin_amdgcn_mfma_f32_16x16x32_bf16(vones, pb, lsum[qg], 0, 0, 0);
#pragma unroll
            for (int dg = 0; dg < 4; dg++)
                o[dg][qg] = __builtin_amdgcn_mfma_f32_16x16x32_bf16(va[dg], pb, o[dg][qg], 0, 0, 0);
            __builtin_amdgcn_s_setprio(0);
        }

        if (kt + 1 < nt) {
            __builtin_amdgcn_s_barrier();
            STAGE_V(kt0 + 64);
        }
    }
#undef STAGE_K
#undef STAGE_V

    __syncthreads();

    float* cmb = (float*)smem;
    float* slab = cmb + (size_t)qw * 2560 + lane * 40;
    if (kw == 1) {
#pragma unroll
        for (int dg = 0; dg < 4; dg++)
#pragma unroll
            for (int qg = 0; qg < 2; qg++)
                *(f32x4_a*)&slab[(dg * 2 + qg) * 4] = o[dg][qg];
#pragma unroll
        for (int qg = 0; qg < 2; qg++)
            *(f32x4_a*)&slab[32 + qg * 4] = lsum[qg];
    }
    __syncthreads();
    if (kw == 0) {
#pragma unroll
        for (int dg = 0; dg < 4; dg++)
#pragma unroll
            for (int qg = 0; qg < 2; qg++) {
                f32x4_a p = *(const f32x4_a*)&slab[(dg * 2 + qg) * 4];
#pragma unroll
                for (int r = 0; r < 4; r++) o[dg][qg][r] += p[r];
            }
#pragma unroll
        for (int qg = 0; qg < 2; qg++) {
            f32x4_a p = *(const f32x4_a*)&slab[32 + qg * 4];
            lsum[qg][0] += p[0];
        }

        const int bb = bh >> 4, hh = bh & 15;
#pragma unroll
        for (int qg = 0; qg < 2; qg++) {
            const float inv = 1.f / lsum[qg][0];
            u16* orow = O + ((size_t)(bb * 2048 + q0w + qg * 16 + fr)) * 1024 + hh * 64 + fq * 4;
#pragma unroll
            for (int dg = 0; dg < 4; dg++) {
                ushort4 h;
                h.x = f2bf(o[dg][qg][0] * inv);
                h.y = f2bf(o[dg][qg][1] * inv);
                h.z = f2bf(o[dg][qg][2] * inv);
                h.w = f2bf(o[dg][qg][3] * inv);
                *(ushort4*)&orow[dg * 16] = h;
            }
        }
    }
}

// ---------------------------------------------------------------------------
extern "C" void kernel_launch(void* const* d_in, const int* in_sizes, int n_in,
                              void* d_out, int out_size, void* d_ws, size_t ws_size,
                              hipStream_t stream) {
    const float* x      = (const float*)d_in[0];
    const float* w_qkv  = (const float*)d_in[1];
    const float* b_qkv  = (const float*)d_in[2];
    const float* w_proj = (const float*)d_in[3];
    const float* b_proj = (const float*)d_in[4];
    float* out = (float*)d_out;

    u16* ws = (u16*)d_ws;
    u16* wqkvT  = ws;                      // 3072*1024
    u16* wprojT = wqkvT + 3072 * 1024;     // 1024*1024
    u16* Qb     = wprojT + 1024 * 1024;    // 32*2048*64
    u16* Kb     = Qb + 32 * 2048 * 64;
    u16* Vtb    = Kb + 32 * 2048 * 64;     // transposed V [BH,64,2048]
    u16* xb     = Vtb + 32 * 2048 * 64;    // x as bf16; reused as attnO
    u16* attnO  = xb;                      // alias (xb dead after gemm1)

    prep_kernel<<<5120, 256, 0, stream>>>(x, xb, w_qkv, wqkvT);

    gemm_8ph<<<dim3(16, 16), 512, 0, stream>>>(xb, wqkvT, b_qkv, Qb, Kb, Vtb);

    attn_kernel<<<2048, 256, 0, stream>>>(Qb, Kb, Vtb, attnO, w_proj, wprojT);

    gemm_m97<64><<<dim3(16, 32), 256, 0, stream>>>(
        attnO, wprojT, b_proj, out, 4096, 1024, 1024);
}

// Round 20
// 91.215 us; speedup vs baseline: 1.2800x; 1.0051x over previous
//
#include <hip/hip_runtime.h>
#include <hip/hip_bf16.h>

typedef short bf16x8 __attribute__((ext_vector_type(8)));
typedef float f32x4 __attribute__((ext_vector_type(4)));
typedef unsigned short u16;
typedef unsigned short u16x8 __attribute__((ext_vector_type(8)));
typedef float f32x4_a __attribute__((ext_vector_type(4), may_alias));

__device__ __forceinline__ u16 f2bf(float f) {
    union { float f; unsigned u; } v; v.f = f;
    unsigned r = v.u + 0x7fffu + ((v.u >> 16) & 1u);
    return (u16)(r >> 16);
}
// pack two f32 -> bf16x2 via the compiler's cvt_pk path (RNE; lo -> low 16)
__device__ __forceinline__ unsigned pk2(float lo, float hi) {
    union { __hip_bfloat162 h; unsigned u; } v;
    v.h = __float22bfloat162_rn(make_float2(lo, hi));
    return v.u;
}

// async global->LDS, 16B per lane. lds base must be wave-uniform (HW adds lane*16).
__device__ __forceinline__ void gld_lds16(const void* g, void* l) {
    __builtin_amdgcn_global_load_lds(
        (const __attribute__((address_space(1))) void*)g,
        (__attribute__((address_space(3))) void*)l, 16, 0, 0);
}

// ---------------------------------------------------------------------------
// Fused prep: x fp32->bf16 (blocks 0..2047), w_qkv transpose+cvt (2048..5119).
// (w_proj transpose rides in the attn launch -- overlaps the attn tail.)
// ---------------------------------------------------------------------------
__global__ __launch_bounds__(256) void prep_kernel(
    const float* __restrict__ x, u16* __restrict__ xb,
    const float* __restrict__ w_qkv, u16* __restrict__ wqkvT) {
    __shared__ float tile[32][33];
    const int b = blockIdx.x, tid = threadIdx.x;
    if (b < 2048) {
        const int i = b * 256 + tid;
        float4 a = ((const float4*)x)[i * 2];
        float4 c = ((const float4*)x)[i * 2 + 1];
        u16x8 h;
        h[0] = f2bf(a.x); h[1] = f2bf(a.y); h[2] = f2bf(a.z); h[3] = f2bf(a.w);
        h[4] = f2bf(c.x); h[5] = f2bf(c.y); h[6] = f2bf(c.z); h[7] = f2bf(c.w);
        *(u16x8*)(xb + (size_t)i * 8) = h;
        return;
    }
    const int bx = b - 2048;           // 3072 tiles: N=3072
    const int n0 = (bx % 96) * 32, k0 = (bx / 96) * 32;
    const int tx = tid & 31, ty = tid >> 5;
#pragma unroll
    for (int i = 0; i < 32; i += 8)
        tile[ty + i][tx] = w_qkv[(size_t)(k0 + ty + i) * 3072 + n0 + tx];
    __syncthreads();
#pragma unroll
    for (int i = 0; i < 32; i += 8)
        wqkvT[(size_t)(n0 + ty + i) * 1024 + k0 + tx] = f2bf(tile[tx][ty + i]);
}

#define QSCALE 0.180336880f  // 0.125 * log2(e)

// ---------------------------------------------------------------------------
// gemm1, 8-wave 3-phase (T3/T4/T5): C = xb[4096,1024] * wqkvT[3072,1024]^T.
// BM=256, BN=192 -> grid 16x16 = 256 blocks = 1/CU (full coverage).
// BK=64, dbuf LDS 112 KB. Per K-tile: issue ALL next-tile DMA up front, then
// 3 phases of 16 MFMAs each {ds-read subtile -> setprio MFMA -> barrier}:
//   A: aR0(mh0)+b01 reads, mh0 x nf01
//   B: b2+aR1(mh1) reads,  (mh0+mh1) x nf2
//   C: (regs live)         mh1 x nf01, then vmcnt(0)+barrier (buffer swap)
// (R19 had 4 phases with two 8-MFMA clusters; merging removes 1 barrier/tile.)
// Epilogue scatters Q (pre-scaled), K as [B,H,T,D]; V transposed [B,H,D,T].
// ---------------------------------------------------------------------------
__global__ __launch_bounds__(512, 2) void gemm_8ph(
    const u16* __restrict__ A, const u16* __restrict__ Bt,
    const float* __restrict__ bias,
    u16* __restrict__ Qo, u16* __restrict__ Ko, u16* __restrict__ Vt) {
    const int K = 1024;
    // lA[2][256*64] @ 0, 16384 ; lB[2][192*64] @ 32768, 45056  (u16 units)
    __shared__ __align__(16) u16 smem[57344];  // 112 KB

    const int tid = threadIdx.x;
    const int lane = tid & 63, wid = tid >> 6;
    const int wm = wid >> 2, wn = wid & 3;     // 2 x 4 wave grid
    const int fr = lane & 15, fq = lane >> 4;
    const int m0 = blockIdx.y * 256, n0 = blockIdx.x * 192;

    const int gsrc = (tid & 7) ^ ((tid >> 3) & 7);
    const u16* gA0 = A + (size_t)(m0 + (tid >> 3)) * K + gsrc * 8;
    const u16* gB0 = Bt + (size_t)(n0 + (tid >> 3)) * K + gsrc * 8;

    const int r7 = fr & 7;
    const int gk0 = ((0 + fq) ^ r7) * 8;
    const int gk1 = ((4 + fq) ^ r7) * 8;

    f32x4 acc[8][3];
#pragma unroll
    for (int m = 0; m < 8; m++)
#pragma unroll
        for (int n = 0; n < 3; n++)
#pragma unroll
            for (int r = 0; r < 4; r++) acc[m][n][r] = 0.f;

#define STAGE8(t)                                                               \
    do {                                                                        \
        const int _b = (t) & 1;                                                 \
        const size_t _ko = (size_t)(t) * 64;                                    \
        u16* _la = smem + _b * 16384 + wid * 512;                               \
        u16* _lb = smem + 32768 + _b * 12288 + wid * 512;                       \
        gld_lds16(gA0 + _ko, _la);                                              \
        gld_lds16(gA0 + (size_t)64 * 1024 + _ko, _la + 4096);                   \
        gld_lds16(gA0 + (size_t)128 * 1024 + _ko, _la + 8192);                  \
        gld_lds16(gA0 + (size_t)192 * 1024 + _ko, _la + 12288);                 \
        gld_lds16(gB0 + _ko, _lb);                                              \
        gld_lds16(gB0 + (size_t)64 * 1024 + _ko, _lb + 4096);                   \
        gld_lds16(gB0 + (size_t)128 * 1024 + _ko, _lb + 8192);                  \
    } while (0)

    STAGE8(0);
    asm volatile("s_waitcnt vmcnt(0)" ::: "memory");
    __builtin_amdgcn_s_barrier();

    for (int t = 0; t < 16; t++) {
        const int b = t & 1;
        const u16* lA = smem + b * 16384;
        const u16* lB = smem + 32768 + b * 12288;
        if (t + 1 < 16) STAGE8(t + 1);  // rides over this tile's 3 phases

        bf16x8 aR0[4][2], aR1[4][2], b01[2][2], b2[2];

        // ---- phase A: read aR0 (mh0) + b01; MFMA mh0 x nf01 (16) ----
#pragma unroll
        for (int mf = 0; mf < 4; mf++) {
            const int row = (wm * 128 + mf * 16 + fr) * 64;
            aR0[mf][0] = *(const bf16x8*)&lA[row + gk0];
            aR0[mf][1] = *(const bf16x8*)&lA[row + gk1];
        }
#pragma unroll
        for (int nf = 0; nf < 2; nf++) {
            const int row = (wn * 48 + nf * 16 + fr) * 64;
            b01[nf][0] = *(const bf16x8*)&lB[row + gk0];
            b01[nf][1] = *(const bf16x8*)&lB[row + gk1];
        }
        __builtin_amdgcn_s_setprio(1);
#pragma unroll
        for (int mf = 0; mf < 4; mf++)
#pragma unroll
            for (int nf = 0; nf < 2; nf++) {
                acc[mf][nf] = __builtin_amdgcn_mfma_f32_16x16x32_bf16(aR0[mf][0], b01[nf][0], acc[mf][nf], 0, 0, 0);
                acc[mf][nf] = __builtin_amdgcn_mfma_f32_16x16x32_bf16(aR0[mf][1], b01[nf][1], acc[mf][nf], 0, 0, 0);
            }
        __builtin_amdgcn_s_setprio(0);
        __builtin_amdgcn_s_barrier();

        // ---- phase B: read b2 + aR1 (mh1); MFMA (mh0+mh1) x nf2 (16) ----
        {
            const int row = (wn * 48 + 32 + fr) * 64;
            b2[0] = *(const bf16x8*)&lB[row + gk0];
            b2[1] = *(const bf16x8*)&lB[row + gk1];
        }
#pragma unroll
        for (int mf = 0; mf < 4; mf++) {
            const int row = (wm * 128 + 64 + mf * 16 + fr) * 64;
            aR1[mf][0] = *(const bf16x8*)&lA[row + gk0];
            aR1[mf][1] = *(const bf16x8*)&lA[row + gk1];
        }
        __builtin_amdgcn_s_setprio(1);
#pragma unroll
        for (int mf = 0; mf < 4; mf++) {
            acc[mf][2] = __builtin_amdgcn_mfma_f32_16x16x32_bf16(aR0[mf][0], b2[0], acc[mf][2], 0, 0, 0);
            acc[mf][2] = __builtin_amdgcn_mfma_f32_16x16x32_bf16(aR0[mf][1], b2[1], acc[mf][2], 0, 0, 0);
        }
#pragma unroll
        for (int mf = 0; mf < 4; mf++) {
            acc[4 + mf][2] = __builtin_amdgcn_mfma_f32_16x16x32_bf16(aR1[mf][0], b2[0], acc[4 + mf][2], 0, 0, 0);
            acc[4 + mf][2] = __builtin_amdgcn_mfma_f32_16x16x32_bf16(aR1[mf][1], b2[1], acc[4 + mf][2], 0, 0, 0);
        }
        __builtin_amdgcn_s_setprio(0);
        __builtin_amdgcn_s_barrier();

        // ---- phase C: MFMA mh1 x nf01 (16; all operands live) ----
        __builtin_amdgcn_s_setprio(1);
#pragma unroll
        for (int mf = 0; mf < 4; mf++)
#pragma unroll
            for (int nf = 0; nf < 2; nf++) {
                acc[4 + mf][nf] = __builtin_amdgcn_mfma_f32_16x16x32_bf16(aR1[mf][0], b01[nf][0], acc[4 + mf][nf], 0, 0, 0);
                acc[4 + mf][nf] = __builtin_amdgcn_mfma_f32_16x16x32_bf16(aR1[mf][1], b01[nf][1], acc[4 + mf][nf], 0, 0, 0);
            }
        __builtin_amdgcn_s_setprio(0);

        // next tile landed + all waves done with buf b
        asm volatile("s_waitcnt vmcnt(0)" ::: "memory");
        __builtin_amdgcn_s_barrier();
    }
#undef STAGE8

    // epilogue: scatter Q/K/V
#pragma unroll
    for (int mf = 0; mf < 8; mf++) {
#pragma unroll
        for (int nf = 0; nf < 3; nf++) {
            const int row0 = m0 + wm * 128 + mf * 16 + fq * 4;
            const int col = n0 + wn * 48 + nf * 16 + fr;
            float v4[4];
#pragma unroll
            for (int r = 0; r < 4; r++) v4[r] = acc[mf][nf][r] + bias[col];
            const int bb = row0 >> 11, t0 = row0 & 2047;
            const int sec = col >> 10, cc = col & 1023;
            const int h = cc >> 6, d = cc & 63;
            if (sec == 0) {
#pragma unroll
                for (int r = 0; r < 4; r++)
                    Qo[(((size_t)(bb * 16 + h) * 2048 + t0 + r) << 6) + d] = f2bf(v4[r] * QSCALE);
            } else if (sec == 1) {
#pragma unroll
                for (int r = 0; r < 4; r++)
                    Ko[(((size_t)(bb * 16 + h) * 2048 + t0 + r) << 6) + d] = f2bf(v4[r]);
            } else {
                ushort4 p;
                p.x = f2bf(v4[0]); p.y = f2bf(v4[1]); p.z = f2bf(v4[2]); p.w = f2bf(v4[3]);
                *(ushort4*)&Vt[(((size_t)(bb * 16 + h) * 64 + d) << 11) + t0] = p;
            }
        }
    }
}

// ---------------------------------------------------------------------------
// GEMM (m97-family) kept for gemm3: C[M,N] = A[M,K](bf16) * Bt[N,K]^T + bias.
// BM=128, BN=64. 4 waves, BK=64, gld_lds staging + both-sides XOR swizzle.
// ---------------------------------------------------------------------------
template <int BN>
__global__ __launch_bounds__(256) void gemm_m97(
    const u16* __restrict__ A, const u16* __restrict__ Bt,
    const float* __restrict__ bias, float* __restrict__ Cf,
    int M, int N, int K) {
    constexpr int NF = BN / 32;
    __shared__ __align__(16) u16 lA[128 * 64];
    __shared__ __align__(16) u16 lB[BN * 64];

    const int tid = threadIdx.x;
    const int lane = tid & 63, wid = tid >> 6;
    const int wr = wid >> 1, wc = wid & 1;
    const int fr = lane & 15, fq = lane >> 4;
    const int m0 = blockIdx.y * 128, n0 = blockIdx.x * BN;

    const int gsrc = (lane & 7) ^ (lane >> 3);
    const u16* gA0 = A + (size_t)(m0 + (tid >> 3)) * K + gsrc * 8;
    const u16* gB0 = Bt + (size_t)(n0 + (tid >> 3)) * K + gsrc * 8;
    u16* lAw = lA + wid * 512;
    u16* lBw = lB + wid * 512;

    const int r7 = fr & 7;
    const int gk[2] = { ((0 + fq) ^ r7) * 8, ((4 + fq) ^ r7) * 8 };

    f32x4 acc[4][NF];
#pragma unroll
    for (int m = 0; m < 4; m++)
#pragma unroll
        for (int n = 0; n < NF; n++)
#pragma unroll
            for (int r = 0; r < 4; r++) acc[m][n][r] = 0.f;

    for (int k0 = 0; k0 < K; k0 += 64) {
        __syncthreads();
#pragma unroll
        for (int c = 0; c < 4; c++)
            gld_lds16(gA0 + (size_t)(c * 32) * K + k0, lAw + c * 2048);
#pragma unroll
        for (int c = 0; c < BN / 32; c++)
            gld_lds16(gB0 + (size_t)(c * 32) * K + k0, lBw + c * 2048);
        __syncthreads();

#pragma unroll
        for (int kf = 0; kf < 2; kf++) {
            bf16x8 a[4], b[NF];
#pragma unroll
            for (int m = 0; m < 4; m++)
                a[m] = *(const bf16x8*)&lA[(wr * 64 + m * 16 + fr) * 64 + gk[kf]];
#pragma unroll
            for (int n = 0; n < NF; n++)
                b[n] = *(const bf16x8*)&lB[(wc * (BN / 2) + n * 16 + fr) * 64 + gk[kf]];
#pragma unroll
            for (int m = 0; m < 4; m++)
#pragma unroll
                for (int n = 0; n < NF; n++)
                    acc[m][n] = __builtin_amdgcn_mfma_f32_16x16x32_bf16(a[m], b[n], acc[m][n], 0, 0, 0);
        }
    }

#pragma unroll
    for (int m = 0; m < 4; m++) {
#pragma unroll
        for (int n = 0; n < NF; n++) {
            const int row0 = m0 + wr * 64 + m * 16 + fq * 4;
            const int col = n0 + wc * (BN / 2) + n * 16 + fr;
#pragma unroll
            for (int r = 0; r < 4; r++)
                Cf[(size_t)(row0 + r) * N + col] = acc[m][n][r] + bias[col];
        }
    }
}

// ---------------------------------------------------------------------------
// Causal flash attention (R18 structure): swapped-operand, 2x2 wave role
// split, in-register P via permlane swaps (pack now via compiler cvt_pk),
// single-buffered V, 24 KB LDS. Blocks >= 1024 do the w_proj transpose.
// ---------------------------------------------------------------------------
__global__ __launch_bounds__(256, 4) void attn_kernel(const u16* __restrict__ Q,
                                                      const u16* __restrict__ Kg,
                                                      const u16* __restrict__ Vt,
                                                      u16* __restrict__ O,
                                                      const float* __restrict__ wp,
                                                      u16* __restrict__ wpT) {
    __shared__ __align__(16) u16 smem[12288];

    const int tid = threadIdx.x;

    if (blockIdx.x >= 1024) {  // ---- w_proj transpose tile ----
        float* tile = (float*)smem;  // [32][33]
        const int bx = blockIdx.x - 1024;
        const int n0 = (bx & 31) * 32, k0 = (bx >> 5) * 32;
        const int tx = tid & 31, ty = tid >> 5;
#pragma unroll
        for (int i = 0; i < 32; i += 8)
            tile[(ty + i) * 33 + tx] = wp[(size_t)(k0 + ty + i) * 1024 + n0 + tx];
        __syncthreads();
#pragma unroll
        for (int i = 0; i < 32; i += 8)
            wpT[(size_t)(n0 + ty + i) * 1024 + k0 + tx] = f2bf(tile[tx * 33 + ty + i]);
        return;
    }

    u16* lV = smem + 8192;
    const int lane = tid & 63, wid = tid >> 6;
    const int fr = lane & 15, fq = lane >> 4;
    const int kw = wid >> 1, qw = wid & 1;
    const int bh = blockIdx.x & 31;
    const int qi = 31 - (blockIdx.x >> 5);
    const int qb0 = qi * 64;
    const size_t base = (size_t)bh * (2048 * 64);
    const u16* Qp = Q + base;
    const u16* Kp = Kg + base;
    const u16* Vp = Vt + base;

    const int q0w = qb0 + qw * 32;
    bf16x8 qa[2][2];
#pragma unroll
    for (int qg = 0; qg < 2; qg++)
#pragma unroll
        for (int kf = 0; kf < 2; kf++)
            qa[qg][kf] = *(const bf16x8*)&Qp[(size_t)(q0w + qg * 16 + fr) * 64 + kf * 32 + fq * 8];

    bf16x8 vones;
#pragma unroll
    for (int j = 0; j < 8; j++) vones[j] = (short)0x3F80;

    f32x4 o[4][2], lsum[2];
#pragma unroll
    for (int qg = 0; qg < 2; qg++) {
#pragma unroll
        for (int r = 0; r < 4; r++) lsum[qg][r] = 0.f;
#pragma unroll
        for (int dg = 0; dg < 4; dg++)
#pragma unroll
            for (int r = 0; r < 4; r++) o[dg][qg][r] = 0.f;
    }

    const int srow0 = wid * 8 + (lane >> 3);
    const int gsrc = (lane & 7) ^ (lane >> 3);
    const u16* kSrc0 = Kp + (size_t)srow0 * 64 + gsrc * 8;
    const u16* vSrc0 = Vp + ((size_t)srow0 << 11) + gsrc * 8;

    const int r7 = fr & 7;
    const int gk0 = ((0 + fq) ^ r7) * 8;
    const int gk1 = ((4 + fq) ^ r7) * 8;
    const int gkv = ((kw * 4 + fq) ^ r7) * 8;

    const int nt = qi + 1;

#define STAGE_K(bufofs, kt0_)                                                   \
    do {                                                                        \
        u16* _lkw = smem + (bufofs) + wid * 512;                                \
        gld_lds16(kSrc0 + (size_t)(kt0_) * 64, _lkw);                           \
        gld_lds16(kSrc0 + (size_t)((kt0_) + 32) * 64, _lkw + 2048);             \
    } while (0)
#define STAGE_V(kt0_)                                                           \
    do {                                                                        \
        u16* _lvw = lV + wid * 512;                                             \
        gld_lds16(vSrc0 + (kt0_), _lvw);                                        \
        gld_lds16(vSrc0 + ((size_t)32 << 11) + (kt0_), _lvw + 2048);            \
    } while (0)

    STAGE_K(0, 0);
    STAGE_V(0);
    asm volatile("s_waitcnt vmcnt(0)" ::: "memory");
    __builtin_amdgcn_s_barrier();

    for (int kt = 0; kt < nt; kt++) {
        const int kt0 = kt << 6;
        const int curofs = (kt & 1) ? 4096 : 0;

        if (kt + 1 < nt) {
            STAGE_K(curofs ^ 4096, kt0 + 64);
            asm volatile("s_waitcnt vmcnt(2)" ::: "memory");
            __builtin_amdgcn_s_barrier();
        } else if (nt > 1) {
            asm volatile("s_waitcnt vmcnt(0)" ::: "memory");
            __builtin_amdgcn_s_barrier();
        }
        const u16* lKc = smem + curofs;

        f32x4 s[2][2];
#pragma unroll
        for (int kg = 0; kg < 2; kg++)
#pragma unroll
            for (int qg = 0; qg < 2; qg++)
#pragma unroll
                for (int r = 0; r < 4; r++) s[kg][qg][r] = 0.f;
        __builtin_amdgcn_s_setprio(1);
#pragma unroll
        for (int kg = 0; kg < 2; kg++) {
            const int krow = (kw * 32 + kg * 16 + fr) * 64;
            bf16x8 kb0 = *(const bf16x8*)&lKc[krow + gk0];
            bf16x8 kb1 = *(const bf16x8*)&lKc[krow + gk1];
#pragma unroll
            for (int qg = 0; qg < 2; qg++) {
                s[kg][qg] = __builtin_amdgcn_mfma_f32_16x16x32_bf16(kb0, qa[qg][0], s[kg][qg], 0, 0, 0);
                s[kg][qg] = __builtin_amdgcn_mfma_f32_16x16x32_bf16(kb1, qa[qg][1], s[kg][qg], 0, 0, 0);
            }
        }
        __builtin_amdgcn_s_setprio(0);

        if (kt == nt - 1) {
#pragma unroll
            for (int kg = 0; kg < 2; kg++) {
                const int kg0 = kt0 + kw * 32 + kg * 16 + fq * 4;
#pragma unroll
                for (int qg = 0; qg < 2; qg++) {
                    const int qg0 = q0w + qg * 16 + fr;
#pragma unroll
                    for (int r = 0; r < 4; r++)
                        if (kg0 + r > qg0) s[kg][qg][r] = -200.f;
                }
            }
        }

        bf16x8 va[4];
#pragma unroll
        for (int dg = 0; dg < 4; dg++)
            va[dg] = *(const bf16x8*)&lV[(dg * 16 + fr) * 64 + gkv];

#pragma unroll
        for (int qg = 0; qg < 2; qg++) {
            unsigned pa = pk2(__builtin_amdgcn_exp2f(s[0][qg][0]), __builtin_amdgcn_exp2f(s[0][qg][1]));
            unsigned pb_ = pk2(__builtin_amdgcn_exp2f(s[0][qg][2]), __builtin_amdgcn_exp2f(s[0][qg][3]));
            unsigned pc = pk2(__builtin_amdgcn_exp2f(s[1][qg][0]), __builtin_amdgcn_exp2f(s[1][qg][1]));
            unsigned pd = pk2(__builtin_amdgcn_exp2f(s[1][qg][2]), __builtin_amdgcn_exp2f(s[1][qg][3]));
            asm("v_permlane32_swap_b32 %0, %1" : "+v"(pa), "+v"(pc));
            asm("v_permlane16_swap_b32 %0, %1" : "+v"(pa), "+v"(pc));
            asm("v_permlane32_swap_b32 %0, %1" : "+v"(pb_), "+v"(pd));
            asm("v_permlane16_swap_b32 %0, %1" : "+v"(pb_), "+v"(pd));
            union { unsigned u[4]; bf16x8 v; } pbu;
            pbu.u[0] = pa; pbu.u[1] = pb_; pbu.u[2] = pc; pbu.u[3] = pd;
            const bf16x8 pb = pbu.v;

            __builtin_amdgcn_s_setprio(1);
            lsum[qg] = __builtin_amdgcn_mfma_f32_16x16x32_bf16(vones, pb, lsum[qg], 0, 0, 0);
#pragma unroll
            for (int dg = 0; dg < 4; dg++)
                o[dg][qg] = __builtin_amdgcn_mfma_f32_16x16x32_bf16(va[dg], pb, o[dg][qg], 0, 0, 0);
            __builtin_amdgcn_s_setprio(0);
        }

        if (kt + 1 < nt) {
            __builtin_amdgcn_s_barrier();
            STAGE_V(kt0 + 64);
        }
    }
#undef STAGE_K
#undef STAGE_V

    __syncthreads();

    float* cmb = (float*)smem;
    float* slab = cmb + (size_t)qw * 2560 + lane * 40;
    if (kw == 1) {
#pragma unroll
        for (int dg = 0; dg < 4; dg++)
#pragma unroll
            for (int qg = 0; qg < 2; qg++)
                *(f32x4_a*)&slab[(dg * 2 + qg) * 4] = o[dg][qg];
#pragma unroll
        for (int qg = 0; qg < 2; qg++)
            *(f32x4_a*)&slab[32 + qg * 4] = lsum[qg];
    }
    __syncthreads();
    if (kw == 0) {
#pragma unroll
        for (int dg = 0; dg < 4; dg++)
#pragma unroll
            for (int qg = 0; qg < 2; qg++) {
                f32x4_a p = *(const f32x4_a*)&slab[(dg * 2 + qg) * 4];
#pragma unroll
                for (int r = 0; r < 4; r++) o[dg][qg][r] += p[r];
            }
#pragma unroll
        for (int qg = 0; qg < 2; qg++) {
            f32x4_a p = *(const f32x4_a*)&slab[32 + qg * 4];
            lsum[qg][0] += p[0];
        }

        const int bb = bh >> 4, hh = bh & 15;
#pragma unroll
        for (int qg = 0; qg < 2; qg++) {
            const float inv = 1.f / lsum[qg][0];
            u16* orow = O + ((size_t)(bb * 2048 + q0w + qg * 16 + fr)) * 1024 + hh * 64 + fq * 4;
#pragma unroll
            for (int dg = 0; dg < 4; dg++) {
                ushort4 h;
                h.x = f2bf(o[dg][qg][0] * inv);
                h.y = f2bf(o[dg][qg][1] * inv);
                h.z = f2bf(o[dg][qg][2] * inv);
                h.w = f2bf(o[dg][qg][3] * inv);
                *(ushort4*)&orow[dg * 16] = h;
            }
        }
    }
}

// ---------------------------------------------------------------------------
extern "C" void kernel_launch(void* const* d_in, const int* in_sizes, int n_in,
                              void* d_out, int out_size, void* d_ws, size_t ws_size,
                              hipStream_t stream) {
    const float* x      = (const float*)d_in[0];
    const float* w_qkv  = (const float*)d_in[1];
    const float* b_qkv  = (const float*)d_in[2];
    const float* w_proj = (const float*)d_in[3];
    const float* b_proj = (const float*)d_in[4];
    float* out = (float*)d_out;

    u16* ws = (u16*)d_ws;
    u16* wqkvT  = ws;                      // 3072*1024
    u16* wprojT = wqkvT + 3072 * 1024;     // 1024*1024
    u16* Qb     = wprojT + 1024 * 1024;    // 32*2048*64
    u16* Kb     = Qb + 32 * 2048 * 64;
    u16* Vtb    = Kb + 32 * 2048 * 64;     // transposed V [BH,64,2048]
    u16* xb     = Vtb + 32 * 2048 * 64;    // x as bf16; reused as attnO
    u16* attnO  = xb;                      // alias (xb dead after gemm1)

    prep_kernel<<<5120, 256, 0, stream>>>(x, xb, w_qkv, wqkvT);

    gemm_8ph<<<dim3(16, 16), 512, 0, stream>>>(xb, wqkvT, b_qkv, Qb, Kb, Vtb);

    attn_kernel<<<2048, 256, 0, stream>>>(Qb, Kb, Vtb, attnO, w_proj, wprojT);

    gemm_m97<64><<<dim3(16, 32), 256, 0, stream>>>(
        attnO, wprojT, b_proj, out, 4096, 1024, 1024);
}

// Round 21
// 90.830 us; speedup vs baseline: 1.2854x; 1.0042x over previous
//
#include <hip/hip_runtime.h>
#include <hip/hip_bf16.h>

typedef short bf16x8 __attribute__((ext_vector_type(8)));
typedef float f32x4 __attribute__((ext_vector_type(4)));
typedef unsigned short u16;
typedef unsigned short u16x8 __attribute__((ext_vector_type(8)));
typedef float f32x4_a __attribute__((ext_vector_type(4), may_alias));

__device__ __forceinline__ u16 f2bf(float f) {
    union { float f; unsigned u; } v; v.f = f;
    unsigned r = v.u + 0x7fffu + ((v.u >> 16) & 1u);
    return (u16)(r >> 16);
}
// pack two f32 -> bf16x2 via the compiler's cvt_pk path (RNE; lo -> low 16)
__device__ __forceinline__ unsigned pk2(float lo, float hi) {
    union { __hip_bfloat162 h; unsigned u; } v;
    v.h = __float22bfloat162_rn(make_float2(lo, hi));
    return v.u;
}

// async global->LDS, 16B per lane. lds base must be wave-uniform (HW adds lane*16).
__device__ __forceinline__ void gld_lds16(const void* g, void* l) {
    __builtin_amdgcn_global_load_lds(
        (const __attribute__((address_space(1))) void*)g,
        (__attribute__((address_space(3))) void*)l, 16, 0, 0);
}

// ---------------------------------------------------------------------------
// Fused prep: x fp32->bf16 (blocks 0..2047), w_qkv transpose+cvt (2048..5119).
// (w_proj transpose rides in the attn launch -- overlaps the attn tail.)
// ---------------------------------------------------------------------------
__global__ __launch_bounds__(256) void prep_kernel(
    const float* __restrict__ x, u16* __restrict__ xb,
    const float* __restrict__ w_qkv, u16* __restrict__ wqkvT) {
    __shared__ float tile[32][33];
    const int b = blockIdx.x, tid = threadIdx.x;
    if (b < 2048) {
        const int i = b * 256 + tid;
        float4 a = ((const float4*)x)[i * 2];
        float4 c = ((const float4*)x)[i * 2 + 1];
        u16x8 h;
        h[0] = f2bf(a.x); h[1] = f2bf(a.y); h[2] = f2bf(a.z); h[3] = f2bf(a.w);
        h[4] = f2bf(c.x); h[5] = f2bf(c.y); h[6] = f2bf(c.z); h[7] = f2bf(c.w);
        *(u16x8*)(xb + (size_t)i * 8) = h;
        return;
    }
    const int bx = b - 2048;           // 3072 tiles: N=3072
    const int n0 = (bx % 96) * 32, k0 = (bx / 96) * 32;
    const int tx = tid & 31, ty = tid >> 5;
#pragma unroll
    for (int i = 0; i < 32; i += 8)
        tile[ty + i][tx] = w_qkv[(size_t)(k0 + ty + i) * 3072 + n0 + tx];
    __syncthreads();
#pragma unroll
    for (int i = 0; i < 32; i += 8)
        wqkvT[(size_t)(n0 + ty + i) * 1024 + k0 + tx] = f2bf(tile[tx][ty + i]);
}

#define QSCALE 0.180336880f  // 0.125 * log2(e)

// ---------------------------------------------------------------------------
// gemm1, 8-wave, 2-BLOCKS/CU: C = xb[4096,1024] * wqkvT[3072,1024]^T.
// BM=128, BN=192 -> grid 16x32 = 512 blocks = 2/CU (16 waves/CU).
// R20's BM=256 variant (112 KB LDS, 1 block/CU) had nothing to overlap the
// per-tile vmcnt(0)+barrier drains with; 80 KB LDS gives a co-resident block
// whose waves fill those shadows (m114 cross-block overlap, the m97 effect).
// BK=64, dbuf; per tile: issue 5 next-tile DMAs up front, then 2 phases
// {aR+b01 reads -> 16 MFMA | b2 read -> 8 MFMA}, one vmcnt(0)/tile.
// Epilogue scatters Q (pre-scaled), K as [B,H,T,D]; V transposed [B,H,D,T].
// ---------------------------------------------------------------------------
__global__ __launch_bounds__(512, 2) void gemm_8ph(
    const u16* __restrict__ A, const u16* __restrict__ Bt,
    const float* __restrict__ bias,
    u16* __restrict__ Qo, u16* __restrict__ Ko, u16* __restrict__ Vt) {
    const int K = 1024;
    // u16 units: lA[2][128*64] @ 0 / 8192 ; lB[2][192*64] @ 16384 / 28672
    __shared__ __align__(16) u16 smem[40960];  // 80 KB -> 2 blocks/CU

    const int tid = threadIdx.x;
    const int lane = tid & 63, wid = tid >> 6;
    const int wm = wid >> 2, wn = wid & 3;     // 2 x 4 wave grid
    const int fr = lane & 15, fq = lane >> 4;
    const int m0 = blockIdx.y * 128, n0 = blockIdx.x * 192;

    // staging: call c covers rows c*64 + (tid>>3); source granule pre-swizzled
    const int gsrc = (tid & 7) ^ ((tid >> 3) & 7);
    const u16* gA0 = A + (size_t)(m0 + (tid >> 3)) * K + gsrc * 8;
    const u16* gB0 = Bt + (size_t)(n0 + (tid >> 3)) * K + gsrc * 8;

    // fragment read granules (same XOR on read)
    const int r7 = fr & 7;
    const int gk0 = ((0 + fq) ^ r7) * 8;
    const int gk1 = ((4 + fq) ^ r7) * 8;

    f32x4 acc[4][3];
#pragma unroll
    for (int m = 0; m < 4; m++)
#pragma unroll
        for (int n = 0; n < 3; n++)
#pragma unroll
            for (int r = 0; r < 4; r++) acc[m][n][r] = 0.f;

#define STAGE5(t)                                                               \
    do {                                                                        \
        const int _b = (t) & 1;                                                 \
        const size_t _ko = (size_t)(t) * 64;                                    \
        u16* _la = smem + _b * 8192 + wid * 512;                                \
        u16* _lb = smem + 16384 + _b * 12288 + wid * 512;                       \
        gld_lds16(gA0 + _ko, _la);                                              \
        gld_lds16(gA0 + (size_t)64 * 1024 + _ko, _la + 4096);                   \
        gld_lds16(gB0 + _ko, _lb);                                              \
        gld_lds16(gB0 + (size_t)64 * 1024 + _ko, _lb + 4096);                   \
        gld_lds16(gB0 + (size_t)128 * 1024 + _ko, _lb + 8192);                  \
    } while (0)

    STAGE5(0);
    asm volatile("s_waitcnt vmcnt(0)" ::: "memory");
    __builtin_amdgcn_s_barrier();

    for (int t = 0; t < 16; t++) {
        const int b = t & 1;
        const u16* lA = smem + b * 8192;
        const u16* lB = smem + 16384 + b * 12288;
        if (t + 1 < 16) STAGE5(t + 1);  // rides over this tile's 2 phases

        bf16x8 aR[4][2], b01[2][2], b2[2];

        // ---- phase A: read aR + b01; MFMA 4mf x 2nf x 2kf (16) ----
#pragma unroll
        for (int mf = 0; mf < 4; mf++) {
            const int row = (wm * 64 + mf * 16 + fr) * 64;
            aR[mf][0] = *(const bf16x8*)&lA[row + gk0];
            aR[mf][1] = *(const bf16x8*)&lA[row + gk1];
        }
#pragma unroll
        for (int nf = 0; nf < 2; nf++) {
            const int row = (wn * 48 + nf * 16 + fr) * 64;
            b01[nf][0] = *(const bf16x8*)&lB[row + gk0];
            b01[nf][1] = *(const bf16x8*)&lB[row + gk1];
        }
        __builtin_amdgcn_s_setprio(1);
#pragma unroll
        for (int mf = 0; mf < 4; mf++)
#pragma unroll
            for (int nf = 0; nf < 2; nf++) {
                acc[mf][nf] = __builtin_amdgcn_mfma_f32_16x16x32_bf16(aR[mf][0], b01[nf][0], acc[mf][nf], 0, 0, 0);
                acc[mf][nf] = __builtin_amdgcn_mfma_f32_16x16x32_bf16(aR[mf][1], b01[nf][1], acc[mf][nf], 0, 0, 0);
            }
        __builtin_amdgcn_s_setprio(0);
        __builtin_amdgcn_s_barrier();

        // ---- phase B: read b2; MFMA 4mf x nf2 x 2kf (8) ----
        {
            const int row = (wn * 48 + 32 + fr) * 64;
            b2[0] = *(const bf16x8*)&lB[row + gk0];
            b2[1] = *(const bf16x8*)&lB[row + gk1];
        }
        __builtin_amdgcn_s_setprio(1);
#pragma unroll
        for (int mf = 0; mf < 4; mf++) {
            acc[mf][2] = __builtin_amdgcn_mfma_f32_16x16x32_bf16(aR[mf][0], b2[0], acc[mf][2], 0, 0, 0);
            acc[mf][2] = __builtin_amdgcn_mfma_f32_16x16x32_bf16(aR[mf][1], b2[1], acc[mf][2], 0, 0, 0);
        }
        __builtin_amdgcn_s_setprio(0);

        // next tile landed + all waves done with buf b
        asm volatile("s_waitcnt vmcnt(0)" ::: "memory");
        __builtin_amdgcn_s_barrier();
    }
#undef STAGE5

    // epilogue: scatter Q/K/V
#pragma unroll
    for (int mf = 0; mf < 4; mf++) {
#pragma unroll
        for (int nf = 0; nf < 3; nf++) {
            const int row0 = m0 + wm * 64 + mf * 16 + fq * 4;
            const int col = n0 + wn * 48 + nf * 16 + fr;
            float v4[4];
#pragma unroll
            for (int r = 0; r < 4; r++) v4[r] = acc[mf][nf][r] + bias[col];
            const int bb = row0 >> 11, t0 = row0 & 2047;
            const int sec = col >> 10, cc = col & 1023;
            const int h = cc >> 6, d = cc & 63;
            if (sec == 0) {
#pragma unroll
                for (int r = 0; r < 4; r++)
                    Qo[(((size_t)(bb * 16 + h) * 2048 + t0 + r) << 6) + d] = f2bf(v4[r] * QSCALE);
            } else if (sec == 1) {
#pragma unroll
                for (int r = 0; r < 4; r++)
                    Ko[(((size_t)(bb * 16 + h) * 2048 + t0 + r) << 6) + d] = f2bf(v4[r]);
            } else {
                ushort4 p;
                p.x = f2bf(v4[0]); p.y = f2bf(v4[1]); p.z = f2bf(v4[2]); p.w = f2bf(v4[3]);
                *(ushort4*)&Vt[(((size_t)(bb * 16 + h) * 64 + d) << 11) + t0] = p;
            }
        }
    }
}

// ---------------------------------------------------------------------------
// GEMM (m97-family) kept for gemm3: C[M,N] = A[M,K](bf16) * Bt[N,K]^T + bias.
// BM=128, BN=64. 4 waves, BK=64, gld_lds staging + both-sides XOR swizzle.
// ---------------------------------------------------------------------------
template <int BN>
__global__ __launch_bounds__(256) void gemm_m97(
    const u16* __restrict__ A, const u16* __restrict__ Bt,
    const float* __restrict__ bias, float* __restrict__ Cf,
    int M, int N, int K) {
    constexpr int NF = BN / 32;
    __shared__ __align__(16) u16 lA[128 * 64];
    __shared__ __align__(16) u16 lB[BN * 64];

    const int tid = threadIdx.x;
    const int lane = tid & 63, wid = tid >> 6;
    const int wr = wid >> 1, wc = wid & 1;
    const int fr = lane & 15, fq = lane >> 4;
    const int m0 = blockIdx.y * 128, n0 = blockIdx.x * BN;

    const int gsrc = (lane & 7) ^ (lane >> 3);
    const u16* gA0 = A + (size_t)(m0 + (tid >> 3)) * K + gsrc * 8;
    const u16* gB0 = Bt + (size_t)(n0 + (tid >> 3)) * K + gsrc * 8;
    u16* lAw = lA + wid * 512;
    u16* lBw = lB + wid * 512;

    const int r7 = fr & 7;
    const int gk[2] = { ((0 + fq) ^ r7) * 8, ((4 + fq) ^ r7) * 8 };

    f32x4 acc[4][NF];
#pragma unroll
    for (int m = 0; m < 4; m++)
#pragma unroll
        for (int n = 0; n < NF; n++)
#pragma unroll
            for (int r = 0; r < 4; r++) acc[m][n][r] = 0.f;

    for (int k0 = 0; k0 < K; k0 += 64) {
        __syncthreads();
#pragma unroll
        for (int c = 0; c < 4; c++)
            gld_lds16(gA0 + (size_t)(c * 32) * K + k0, lAw + c * 2048);
#pragma unroll
        for (int c = 0; c < BN / 32; c++)
            gld_lds16(gB0 + (size_t)(c * 32) * K + k0, lBw + c * 2048);
        __syncthreads();

#pragma unroll
        for (int kf = 0; kf < 2; kf++) {
            bf16x8 a[4], b[NF];
#pragma unroll
            for (int m = 0; m < 4; m++)
                a[m] = *(const bf16x8*)&lA[(wr * 64 + m * 16 + fr) * 64 + gk[kf]];
#pragma unroll
            for (int n = 0; n < NF; n++)
                b[n] = *(const bf16x8*)&lB[(wc * (BN / 2) + n * 16 + fr) * 64 + gk[kf]];
#pragma unroll
            for (int m = 0; m < 4; m++)
#pragma unroll
                for (int n = 0; n < NF; n++)
                    acc[m][n] = __builtin_amdgcn_mfma_f32_16x16x32_bf16(a[m], b[n], acc[m][n], 0, 0, 0);
        }
    }

#pragma unroll
    for (int m = 0; m < 4; m++) {
#pragma unroll
        for (int n = 0; n < NF; n++) {
            const int row0 = m0 + wr * 64 + m * 16 + fq * 4;
            const int col = n0 + wc * (BN / 2) + n * 16 + fr;
#pragma unroll
            for (int r = 0; r < 4; r++)
                Cf[(size_t)(row0 + r) * N + col] = acc[m][n][r] + bias[col];
        }
    }
}

// ---------------------------------------------------------------------------
// Causal flash attention (R18 structure): swapped-operand, 2x2 wave role
// split, in-register P via permlane swaps (pack via compiler cvt_pk),
// single-buffered V, 24 KB LDS. Blocks >= 1024 do the w_proj transpose.
// ---------------------------------------------------------------------------
__global__ __launch_bounds__(256, 4) void attn_kernel(const u16* __restrict__ Q,
                                                      const u16* __restrict__ Kg,
                                                      const u16* __restrict__ Vt,
                                                      u16* __restrict__ O,
                                                      const float* __restrict__ wp,
                                                      u16* __restrict__ wpT) {
    __shared__ __align__(16) u16 smem[12288];

    const int tid = threadIdx.x;

    if (blockIdx.x >= 1024) {  // ---- w_proj transpose tile ----
        float* tile = (float*)smem;  // [32][33]
        const int bx = blockIdx.x - 1024;
        const int n0 = (bx & 31) * 32, k0 = (bx >> 5) * 32;
        const int tx = tid & 31, ty = tid >> 5;
#pragma unroll
        for (int i = 0; i < 32; i += 8)
            tile[(ty + i) * 33 + tx] = wp[(size_t)(k0 + ty + i) * 1024 + n0 + tx];
        __syncthreads();
#pragma unroll
        for (int i = 0; i < 32; i += 8)
            wpT[(size_t)(n0 + ty + i) * 1024 + k0 + tx] = f2bf(tile[tx * 33 + ty + i]);
        return;
    }

    u16* lV = smem + 8192;
    const int lane = tid & 63, wid = tid >> 6;
    const int fr = lane & 15, fq = lane >> 4;
    const int kw = wid >> 1, qw = wid & 1;
    const int bh = blockIdx.x & 31;
    const int qi = 31 - (blockIdx.x >> 5);
    const int qb0 = qi * 64;
    const size_t base = (size_t)bh * (2048 * 64);
    const u16* Qp = Q + base;
    const u16* Kp = Kg + base;
    const u16* Vp = Vt + base;

    const int q0w = qb0 + qw * 32;
    bf16x8 qa[2][2];
#pragma unroll
    for (int qg = 0; qg < 2; qg++)
#pragma unroll
        for (int kf = 0; kf < 2; kf++)
            qa[qg][kf] = *(const bf16x8*)&Qp[(size_t)(q0w + qg * 16 + fr) * 64 + kf * 32 + fq * 8];

    bf16x8 vones;
#pragma unroll
    for (int j = 0; j < 8; j++) vones[j] = (short)0x3F80;

    f32x4 o[4][2], lsum[2];
#pragma unroll
    for (int qg = 0; qg < 2; qg++) {
#pragma unroll
        for (int r = 0; r < 4; r++) lsum[qg][r] = 0.f;
#pragma unroll
        for (int dg = 0; dg < 4; dg++)
#pragma unroll
            for (int r = 0; r < 4; r++) o[dg][qg][r] = 0.f;
    }

    const int srow0 = wid * 8 + (lane >> 3);
    const int gsrc = (lane & 7) ^ (lane >> 3);
    const u16* kSrc0 = Kp + (size_t)srow0 * 64 + gsrc * 8;
    const u16* vSrc0 = Vp + ((size_t)srow0 << 11) + gsrc * 8;

    const int r7 = fr & 7;
    const int gk0 = ((0 + fq) ^ r7) * 8;
    const int gk1 = ((4 + fq) ^ r7) * 8;
    const int gkv = ((kw * 4 + fq) ^ r7) * 8;

    const int nt = qi + 1;

#define STAGE_K(bufofs, kt0_)                                                   \
    do {                                                                        \
        u16* _lkw = smem + (bufofs) + wid * 512;                                \
        gld_lds16(kSrc0 + (size_t)(kt0_) * 64, _lkw);                           \
        gld_lds16(kSrc0 + (size_t)((kt0_) + 32) * 64, _lkw + 2048);             \
    } while (0)
#define STAGE_V(kt0_)                                                           \
    do {                                                                        \
        u16* _lvw = lV + wid * 512;                                             \
        gld_lds16(vSrc0 + (kt0_), _lvw);                                        \
        gld_lds16(vSrc0 + ((size_t)32 << 11) + (kt0_), _lvw + 2048);            \
    } while (0)

    STAGE_K(0, 0);
    STAGE_V(0);
    asm volatile("s_waitcnt vmcnt(0)" ::: "memory");
    __builtin_amdgcn_s_barrier();

    for (int kt = 0; kt < nt; kt++) {
        const int kt0 = kt << 6;
        const int curofs = (kt & 1) ? 4096 : 0;

        if (kt + 1 < nt) {
            STAGE_K(curofs ^ 4096, kt0 + 64);
            asm volatile("s_waitcnt vmcnt(2)" ::: "memory");
            __builtin_amdgcn_s_barrier();
        } else if (nt > 1) {
            asm volatile("s_waitcnt vmcnt(0)" ::: "memory");
            __builtin_amdgcn_s_barrier();
        }
        const u16* lKc = smem + curofs;

        f32x4 s[2][2];
#pragma unroll
        for (int kg = 0; kg < 2; kg++)
#pragma unroll
            for (int qg = 0; qg < 2; qg++)
#pragma unroll
                for (int r = 0; r < 4; r++) s[kg][qg][r] = 0.f;
        __builtin_amdgcn_s_setprio(1);
#pragma unroll
        for (int kg = 0; kg < 2; kg++) {
            const int krow = (kw * 32 + kg * 16 + fr) * 64;
            bf16x8 kb0 = *(const bf16x8*)&lKc[krow + gk0];
            bf16x8 kb1 = *(const bf16x8*)&lKc[krow + gk1];
#pragma unroll
            for (int qg = 0; qg < 2; qg++) {
                s[kg][qg] = __builtin_amdgcn_mfma_f32_16x16x32_bf16(kb0, qa[qg][0], s[kg][qg], 0, 0, 0);
                s[kg][qg] = __builtin_amdgcn_mfma_f32_16x16x32_bf16(kb1, qa[qg][1], s[kg][qg], 0, 0, 0);
            }
        }
        __builtin_amdgcn_s_setprio(0);

        if (kt == nt - 1) {
#pragma unroll
            for (int kg = 0; kg < 2; kg++) {
                const int kg0 = kt0 + kw * 32 + kg * 16 + fq * 4;
#pragma unroll
                for (int qg = 0; qg < 2; qg++) {
                    const int qg0 = q0w + qg * 16 + fr;
#pragma unroll
                    for (int r = 0; r < 4; r++)
                        if (kg0 + r > qg0) s[kg][qg][r] = -200.f;
                }
            }
        }

        bf16x8 va[4];
#pragma unroll
        for (int dg = 0; dg < 4; dg++)
            va[dg] = *(const bf16x8*)&lV[(dg * 16 + fr) * 64 + gkv];

#pragma unroll
        for (int qg = 0; qg < 2; qg++) {
            unsigned pa = pk2(__builtin_amdgcn_exp2f(s[0][qg][0]), __builtin_amdgcn_exp2f(s[0][qg][1]));
            unsigned pb_ = pk2(__builtin_amdgcn_exp2f(s[0][qg][2]), __builtin_amdgcn_exp2f(s[0][qg][3]));
            unsigned pc = pk2(__builtin_amdgcn_exp2f(s[1][qg][0]), __builtin_amdgcn_exp2f(s[1][qg][1]));
            unsigned pd = pk2(__builtin_amdgcn_exp2f(s[1][qg][2]), __builtin_amdgcn_exp2f(s[1][qg][3]));
            asm("v_permlane32_swap_b32 %0, %1" : "+v"(pa), "+v"(pc));
            asm("v_permlane16_swap_b32 %0, %1" : "+v"(pa), "+v"(pc));
            asm("v_permlane32_swap_b32 %0, %1" : "+v"(pb_), "+v"(pd));
            asm("v_permlane16_swap_b32 %0, %1" : "+v"(pb_), "+v"(pd));
            union { unsigned u[4]; bf16x8 v; } pbu;
            pbu.u[0] = pa; pbu.u[1] = pb_; pbu.u[2] = pc; pbu.u[3] = pd;
            const bf16x8 pb = pbu.v;

            __builtin_amdgcn_s_setprio(1);
            lsum[qg] = __builtin_amdgcn_mfma_f32_16x16x32_bf16(vones, pb, lsum[qg], 0, 0, 0);
#pragma unroll
            for (int dg = 0; dg < 4; dg++)
                o[dg][qg] = __builtin_amdgcn_mfma_f32_16x16x32_bf16(va[dg], pb, o[dg][qg], 0, 0, 0);
            __builtin_amdgcn_s_setprio(0);
        }

        if (kt + 1 < nt) {
            __builtin_amdgcn_s_barrier();
            STAGE_V(kt0 + 64);
        }
    }
#undef STAGE_K
#undef STAGE_V

    __syncthreads();

    float* cmb = (float*)smem;
    float* slab = cmb + (size_t)qw * 2560 + lane * 40;
    if (kw == 1) {
#pragma unroll
        for (int dg = 0; dg < 4; dg++)
#pragma unroll
            for (int qg = 0; qg < 2; qg++)
                *(f32x4_a*)&slab[(dg * 2 + qg) * 4] = o[dg][qg];
#pragma unroll
        for (int qg = 0; qg < 2; qg++)
            *(f32x4_a*)&slab[32 + qg * 4] = lsum[qg];
    }
    __syncthreads();
    if (kw == 0) {
#pragma unroll
        for (int dg = 0; dg < 4; dg++)
#pragma unroll
            for (int qg = 0; qg < 2; qg++) {
                f32x4_a p = *(const f32x4_a*)&slab[(dg * 2 + qg) * 4];
#pragma unroll
                for (int r = 0; r < 4; r++) o[dg][qg][r] += p[r];
            }
#pragma unroll
        for (int qg = 0; qg < 2; qg++) {
            f32x4_a p = *(const f32x4_a*)&slab[32 + qg * 4];
            lsum[qg][0] += p[0];
        }

        const int bb = bh >> 4, hh = bh & 15;
#pragma unroll
        for (int qg = 0; qg < 2; qg++) {
            const float inv = 1.f / lsum[qg][0];
            u16* orow = O + ((size_t)(bb * 2048 + q0w + qg * 16 + fr)) * 1024 + hh * 64 + fq * 4;
#pragma unroll
            for (int dg = 0; dg < 4; dg++) {
                ushort4 h;
                h.x = f2bf(o[dg][qg][0] * inv);
                h.y = f2bf(o[dg][qg][1] * inv);
                h.z = f2bf(o[dg][qg][2] * inv);
                h.w = f2bf(o[dg][qg][3] * inv);
                *(ushort4*)&orow[dg * 16] = h;
            }
        }
    }
}

// ---------------------------------------------------------------------------
extern "C" void kernel_launch(void* const* d_in, const int* in_sizes, int n_in,
                              void* d_out, int out_size, void* d_ws, size_t ws_size,
                              hipStream_t stream) {
    const float* x      = (const float*)d_in[0];
    const float* w_qkv  = (const float*)d_in[1];
    const float* b_qkv  = (const float*)d_in[2];
    const float* w_proj = (const float*)d_in[3];
    const float* b_proj = (const float*)d_in[4];
    float* out = (float*)d_out;

    u16* ws = (u16*)d_ws;
    u16* wqkvT  = ws;                      // 3072*1024
    u16* wprojT = wqkvT + 3072 * 1024;     // 1024*1024
    u16* Qb     = wprojT + 1024 * 1024;    // 32*2048*64
    u16* Kb     = Qb + 32 * 2048 * 64;
    u16* Vtb    = Kb + 32 * 2048 * 64;     // transposed V [BH,64,2048]
    u16* xb     = Vtb + 32 * 2048 * 64;    // x as bf16; reused as attnO
    u16* attnO  = xb;                      // alias (xb dead after gemm1)

    prep_kernel<<<5120, 256, 0, stream>>>(x, xb, w_qkv, wqkvT);

    gemm_8ph<<<dim3(16, 32), 512, 0, stream>>>(xb, wqkvT, b_qkv, Qb, Kb, Vtb);

    attn_kernel<<<2048, 256, 0, stream>>>(Qb, Kb, Vtb, attnO, w_proj, wprojT);

    gemm_m97<64><<<dim3(16, 32), 256, 0, stream>>>(
        attnO, wprojT, b_proj, out, 4096, 1024, 1024);
}

// Round 22
// 90.827 us; speedup vs baseline: 1.2855x; 1.0000x over previous
//
#include <hip/hip_runtime.h>
#include <hip/hip_bf16.h>

typedef short bf16x8 __attribute__((ext_vector_type(8)));
typedef float f32x4 __attribute__((ext_vector_type(4)));
typedef unsigned short u16;
typedef unsigned short u16x8 __attribute__((ext_vector_type(8)));
typedef float f32x4_a __attribute__((ext_vector_type(4), may_alias));

__device__ __forceinline__ u16 f2bf(float f) {
    union { float f; unsigned u; } v; v.f = f;
    unsigned r = v.u + 0x7fffu + ((v.u >> 16) & 1u);
    return (u16)(r >> 16);
}
// pack two f32 -> bf16x2 via the compiler's cvt_pk path (RNE; lo -> low 16)
__device__ __forceinline__ unsigned pk2(float lo, float hi) {
    union { __hip_bfloat162 h; unsigned u; } v;
    v.h = __float22bfloat162_rn(make_float2(lo, hi));
    return v.u;
}

// async global->LDS, 16B per lane. lds base must be wave-uniform (HW adds lane*16).
__device__ __forceinline__ void gld_lds16(const void* g, void* l) {
    __builtin_amdgcn_global_load_lds(
        (const __attribute__((address_space(1))) void*)g,
        (__attribute__((address_space(3))) void*)l, 16, 0, 0);
}

// ---------------------------------------------------------------------------
// Fused prep: x fp32->bf16 (blocks 0..2047), w_qkv transpose+cvt (2048..5119).
// ---------------------------------------------------------------------------
__global__ __launch_bounds__(256) void prep_kernel(
    const float* __restrict__ x, u16* __restrict__ xb,
    const float* __restrict__ w_qkv, u16* __restrict__ wqkvT) {
    __shared__ float tile[32][33];
    const int b = blockIdx.x, tid = threadIdx.x;
    if (b < 2048) {
        const int i = b * 256 + tid;
        float4 a = ((const float4*)x)[i * 2];
        float4 c = ((const float4*)x)[i * 2 + 1];
        u16x8 h;
        h[0] = f2bf(a.x); h[1] = f2bf(a.y); h[2] = f2bf(a.z); h[3] = f2bf(a.w);
        h[4] = f2bf(c.x); h[5] = f2bf(c.y); h[6] = f2bf(c.z); h[7] = f2bf(c.w);
        *(u16x8*)(xb + (size_t)i * 8) = h;
        return;
    }
    const int bx = b - 2048;           // 3072 tiles: N=3072
    const int n0 = (bx % 96) * 32, k0 = (bx / 96) * 32;
    const int tx = tid & 31, ty = tid >> 5;
#pragma unroll
    for (int i = 0; i < 32; i += 8)
        tile[ty + i][tx] = w_qkv[(size_t)(k0 + ty + i) * 3072 + n0 + tx];
    __syncthreads();
#pragma unroll
    for (int i = 0; i < 32; i += 8)
        wqkvT[(size_t)(n0 + ty + i) * 1024 + k0 + tx] = f2bf(tile[tx][ty + i]);
}

#define QSCALE 0.180336880f  // 0.125 * log2(e)

// ---------------------------------------------------------------------------
// gemm1, 4-wave BIG-TILE-PER-WAVE: C = xb[4096,1024] * wqkvT[3072,1024]^T.
// BM=128, BN=192, grid 16x32 = 512 blocks = 2/CU. 4 waves (2m x 2n), wave
// tile 64x96: 20 ds_read_b128 per 48 MFMAs (0.42 reads/MFMA vs R21's 0.58)
// -- attacks the per-wave DS-issue serialization that pinned R21 at ~950 TF.
// BK=64, dbuf 80 KB; per tile: issue 10 next-tile DMAs up front, 2 phases
// {aR+b012 reads -> 24 MFMA | b345 reads -> 24 MFMA}, one vmcnt(0)/tile.
// Epilogue scatters Q (pre-scaled), K as [B,H,T,D]; V transposed [B,H,D,T].
// ---------------------------------------------------------------------------
__global__ __launch_bounds__(256, 2) void gemm_8ph(
    const u16* __restrict__ A, const u16* __restrict__ Bt,
    const float* __restrict__ bias,
    u16* __restrict__ Qo, u16* __restrict__ Ko, u16* __restrict__ Vt) {
    const int K = 1024;
    // u16 units: lA[2][128*64] @ 0 / 8192 ; lB[2][192*64] @ 16384 / 28672
    __shared__ __align__(16) u16 smem[40960];  // 80 KB -> 2 blocks/CU

    const int tid = threadIdx.x;
    const int lane = tid & 63, wid = tid >> 6;
    const int wm = wid >> 1, wn = wid & 1;     // 2 x 2 wave grid, 64x96 each
    const int fr = lane & 15, fq = lane >> 4;
    const int m0 = blockIdx.y * 128, n0 = blockIdx.x * 192;

    // staging: 256-thread call covers 32 rows (tid>>3 = 0..31); granule
    // pre-swizzled by row&7 (rule #21); call c adds c*32 rows.
    const int gsrc = (tid & 7) ^ ((tid >> 3) & 7);
    const u16* gA0 = A + (size_t)(m0 + (tid >> 3)) * K + gsrc * 8;
    const u16* gB0 = Bt + (size_t)(n0 + (tid >> 3)) * K + gsrc * 8;

    // fragment read granules (same XOR on read)
    const int r7 = fr & 7;
    const int gk0 = ((0 + fq) ^ r7) * 8;
    const int gk1 = ((4 + fq) ^ r7) * 8;

    f32x4 acc[4][6];
#pragma unroll
    for (int m = 0; m < 4; m++)
#pragma unroll
        for (int n = 0; n < 6; n++)
#pragma unroll
            for (int r = 0; r < 4; r++) acc[m][n][r] = 0.f;

#define STAGE10(t)                                                              \
    do {                                                                        \
        const int _b = (t) & 1;                                                 \
        const size_t _ko = (size_t)(t) * 64;                                    \
        u16* _la = smem + _b * 8192 + wid * 512;                                \
        u16* _lb = smem + 16384 + _b * 12288 + wid * 512;                       \
        gld_lds16(gA0 + _ko, _la);                                              \
        gld_lds16(gA0 + (size_t)32 * 1024 + _ko, _la + 2048);                   \
        gld_lds16(gA0 + (size_t)64 * 1024 + _ko, _la + 4096);                   \
        gld_lds16(gA0 + (size_t)96 * 1024 + _ko, _la + 6144);                   \
        gld_lds16(gB0 + _ko, _lb);                                              \
        gld_lds16(gB0 + (size_t)32 * 1024 + _ko, _lb + 2048);                   \
        gld_lds16(gB0 + (size_t)64 * 1024 + _ko, _lb + 4096);                   \
        gld_lds16(gB0 + (size_t)96 * 1024 + _ko, _lb + 6144);                   \
        gld_lds16(gB0 + (size_t)128 * 1024 + _ko, _lb + 8192);                  \
        gld_lds16(gB0 + (size_t)160 * 1024 + _ko, _lb + 10240);                 \
    } while (0)

    STAGE10(0);
    asm volatile("s_waitcnt vmcnt(0)" ::: "memory");
    __builtin_amdgcn_s_barrier();

    for (int t = 0; t < 16; t++) {
        const int b = t & 1;
        const u16* lA = smem + b * 8192;
        const u16* lB = smem + 16384 + b * 12288;
        if (t + 1 < 16) STAGE10(t + 1);  // rides over this tile's 2 phases

        bf16x8 aR[4][2], bR[3][2];

        // ---- phase A: read aR (8) + b[0..2] (6); MFMA 4mf x 3nf x 2kf (24)
#pragma unroll
        for (int mf = 0; mf < 4; mf++) {
            const int row = (wm * 64 + mf * 16 + fr) * 64;
            aR[mf][0] = *(const bf16x8*)&lA[row + gk0];
            aR[mf][1] = *(const bf16x8*)&lA[row + gk1];
        }
#pragma unroll
        for (int nf = 0; nf < 3; nf++) {
            const int row = (wn * 96 + nf * 16 + fr) * 64;
            bR[nf][0] = *(const bf16x8*)&lB[row + gk0];
            bR[nf][1] = *(const bf16x8*)&lB[row + gk1];
        }
        __builtin_amdgcn_s_setprio(1);
#pragma unroll
        for (int mf = 0; mf < 4; mf++)
#pragma unroll
            for (int nf = 0; nf < 3; nf++) {
                acc[mf][nf] = __builtin_amdgcn_mfma_f32_16x16x32_bf16(aR[mf][0], bR[nf][0], acc[mf][nf], 0, 0, 0);
                acc[mf][nf] = __builtin_amdgcn_mfma_f32_16x16x32_bf16(aR[mf][1], bR[nf][1], acc[mf][nf], 0, 0, 0);
            }
        __builtin_amdgcn_s_setprio(0);
        __builtin_amdgcn_s_barrier();

        // ---- phase B: read b[3..5] (6); MFMA 4mf x 3nf x 2kf (24)
#pragma unroll
        for (int nf = 0; nf < 3; nf++) {
            const int row = (wn * 96 + (nf + 3) * 16 + fr) * 64;
            bR[nf][0] = *(const bf16x8*)&lB[row + gk0];
            bR[nf][1] = *(const bf16x8*)&lB[row + gk1];
        }
        __builtin_amdgcn_s_setprio(1);
#pragma unroll
        for (int mf = 0; mf < 4; mf++)
#pragma unroll
            for (int nf = 0; nf < 3; nf++) {
                acc[mf][nf + 3] = __builtin_amdgcn_mfma_f32_16x16x32_bf16(aR[mf][0], bR[nf][0], acc[mf][nf + 3], 0, 0, 0);
                acc[mf][nf + 3] = __builtin_amdgcn_mfma_f32_16x16x32_bf16(aR[mf][1], bR[nf][1], acc[mf][nf + 3], 0, 0, 0);
            }
        __builtin_amdgcn_s_setprio(0);

        // next tile landed + all waves done with buf b
        asm volatile("s_waitcnt vmcnt(0)" ::: "memory");
        __builtin_amdgcn_s_barrier();
    }
#undef STAGE10

    // epilogue: scatter Q/K/V
#pragma unroll
    for (int mf = 0; mf < 4; mf++) {
#pragma unroll
        for (int nf = 0; nf < 6; nf++) {
            const int row0 = m0 + wm * 64 + mf * 16 + fq * 4;
            const int col = n0 + wn * 96 + nf * 16 + fr;
            float v4[4];
#pragma unroll
            for (int r = 0; r < 4; r++) v4[r] = acc[mf][nf][r] + bias[col];
            const int bb = row0 >> 11, t0 = row0 & 2047;
            const int sec = col >> 10, cc = col & 1023;
            const int h = cc >> 6, d = cc & 63;
            if (sec == 0) {
#pragma unroll
                for (int r = 0; r < 4; r++)
                    Qo[(((size_t)(bb * 16 + h) * 2048 + t0 + r) << 6) + d] = f2bf(v4[r] * QSCALE);
            } else if (sec == 1) {
#pragma unroll
                for (int r = 0; r < 4; r++)
                    Ko[(((size_t)(bb * 16 + h) * 2048 + t0 + r) << 6) + d] = f2bf(v4[r]);
            } else {
                ushort4 p;
                p.x = f2bf(v4[0]); p.y = f2bf(v4[1]); p.z = f2bf(v4[2]); p.w = f2bf(v4[3]);
                *(ushort4*)&Vt[(((size_t)(bb * 16 + h) * 64 + d) << 11) + t0] = p;
            }
        }
    }
}

// ---------------------------------------------------------------------------
// GEMM (m97-family) kept for gemm3: C[M,N] = A[M,K](bf16) * Bt[N,K]^T + bias.
// ---------------------------------------------------------------------------
template <int BN>
__global__ __launch_bounds__(256) void gemm_m97(
    const u16* __restrict__ A, const u16* __restrict__ Bt,
    const float* __restrict__ bias, float* __restrict__ Cf,
    int M, int N, int K) {
    constexpr int NF = BN / 32;
    __shared__ __align__(16) u16 lA[128 * 64];
    __shared__ __align__(16) u16 lB[BN * 64];

    const int tid = threadIdx.x;
    const int lane = tid & 63, wid = tid >> 6;
    const int wr = wid >> 1, wc = wid & 1;
    const int fr = lane & 15, fq = lane >> 4;
    const int m0 = blockIdx.y * 128, n0 = blockIdx.x * BN;

    const int gsrc = (lane & 7) ^ (lane >> 3);
    const u16* gA0 = A + (size_t)(m0 + (tid >> 3)) * K + gsrc * 8;
    const u16* gB0 = Bt + (size_t)(n0 + (tid >> 3)) * K + gsrc * 8;
    u16* lAw = lA + wid * 512;
    u16* lBw = lB + wid * 512;

    const int r7 = fr & 7;
    const int gk[2] = { ((0 + fq) ^ r7) * 8, ((4 + fq) ^ r7) * 8 };

    f32x4 acc[4][NF];
#pragma unroll
    for (int m = 0; m < 4; m++)
#pragma unroll
        for (int n = 0; n < NF; n++)
#pragma unroll
            for (int r = 0; r < 4; r++) acc[m][n][r] = 0.f;

    for (int k0 = 0; k0 < K; k0 += 64) {
        __syncthreads();
#pragma unroll
        for (int c = 0; c < 4; c++)
            gld_lds16(gA0 + (size_t)(c * 32) * K + k0, lAw + c * 2048);
#pragma unroll
        for (int c = 0; c < BN / 32; c++)
            gld_lds16(gB0 + (size_t)(c * 32) * K + k0, lBw + c * 2048);
        __syncthreads();

#pragma unroll
        for (int kf = 0; kf < 2; kf++) {
            bf16x8 a[4], b[NF];
#pragma unroll
            for (int m = 0; m < 4; m++)
                a[m] = *(const bf16x8*)&lA[(wr * 64 + m * 16 + fr) * 64 + gk[kf]];
#pragma unroll
            for (int n = 0; n < NF; n++)
                b[n] = *(const bf16x8*)&lB[(wc * (BN / 2) + n * 16 + fr) * 64 + gk[kf]];
#pragma unroll
            for (int m = 0; m < 4; m++)
#pragma unroll
                for (int n = 0; n < NF; n++)
                    acc[m][n] = __builtin_amdgcn_mfma_f32_16x16x32_bf16(a[m], b[n], acc[m][n], 0, 0, 0);
        }
    }

#pragma unroll
    for (int m = 0; m < 4; m++) {
#pragma unroll
        for (int n = 0; n < NF; n++) {
            const int row0 = m0 + wr * 64 + m * 16 + fq * 4;
            const int col = n0 + wc * (BN / 2) + n * 16 + fr;
#pragma unroll
            for (int r = 0; r < 4; r++)
                Cf[(size_t)(row0 + r) * N + col] = acc[m][n][r] + bias[col];
        }
    }
}

// ---------------------------------------------------------------------------
// Causal flash attention (R18 structure, frozen): swapped-operand, 2x2 wave
// role split, in-register P via permlane swaps, single-buffered V, 24 KB LDS.
// Blocks >= 1024 do the w_proj transpose.
// ---------------------------------------------------------------------------
__global__ __launch_bounds__(256, 4) void attn_kernel(const u16* __restrict__ Q,
                                                      const u16* __restrict__ Kg,
                                                      const u16* __restrict__ Vt,
                                                      u16* __restrict__ O,
                                                      const float* __restrict__ wp,
                                                      u16* __restrict__ wpT) {
    __shared__ __align__(16) u16 smem[12288];

    const int tid = threadIdx.x;

    if (blockIdx.x >= 1024) {  // ---- w_proj transpose tile ----
        float* tile = (float*)smem;  // [32][33]
        const int bx = blockIdx.x - 1024;
        const int n0 = (bx & 31) * 32, k0 = (bx >> 5) * 32;
        const int tx = tid & 31, ty = tid >> 5;
#pragma unroll
        for (int i = 0; i < 32; i += 8)
            tile[(ty + i) * 33 + tx] = wp[(size_t)(k0 + ty + i) * 1024 + n0 + tx];
        __syncthreads();
#pragma unroll
        for (int i = 0; i < 32; i += 8)
            wpT[(size_t)(n0 + ty + i) * 1024 + k0 + tx] = f2bf(tile[tx * 33 + ty + i]);
        return;
    }

    u16* lV = smem + 8192;
    const int lane = tid & 63, wid = tid >> 6;
    const int fr = lane & 15, fq = lane >> 4;
    const int kw = wid >> 1, qw = wid & 1;
    const int bh = blockIdx.x & 31;
    const int qi = 31 - (blockIdx.x >> 5);
    const int qb0 = qi * 64;
    const size_t base = (size_t)bh * (2048 * 64);
    const u16* Qp = Q + base;
    const u16* Kp = Kg + base;
    const u16* Vp = Vt + base;

    const int q0w = qb0 + qw * 32;
    bf16x8 qa[2][2];
#pragma unroll
    for (int qg = 0; qg < 2; qg++)
#pragma unroll
        for (int kf = 0; kf < 2; kf++)
            qa[qg][kf] = *(const bf16x8*)&Qp[(size_t)(q0w + qg * 16 + fr) * 64 + kf * 32 + fq * 8];

    bf16x8 vones;
#pragma unroll
    for (int j = 0; j < 8; j++) vones[j] = (short)0x3F80;

    f32x4 o[4][2], lsum[2];
#pragma unroll
    for (int qg = 0; qg < 2; qg++) {
#pragma unroll
        for (int r = 0; r < 4; r++) lsum[qg][r] = 0.f;
#pragma unroll
        for (int dg = 0; dg < 4; dg++)
#pragma unroll
            for (int r = 0; r < 4; r++) o[dg][qg][r] = 0.f;
    }

    const int srow0 = wid * 8 + (lane >> 3);
    const int gsrc = (lane & 7) ^ (lane >> 3);
    const u16* kSrc0 = Kp + (size_t)srow0 * 64 + gsrc * 8;
    const u16* vSrc0 = Vp + ((size_t)srow0 << 11) + gsrc * 8;

    const int r7 = fr & 7;
    const int gk0 = ((0 + fq) ^ r7) * 8;
    const int gk1 = ((4 + fq) ^ r7) * 8;
    const int gkv = ((kw * 4 + fq) ^ r7) * 8;

    const int nt = qi + 1;

#define STAGE_K(bufofs, kt0_)                                                   \
    do {                                                                        \
        u16* _lkw = smem + (bufofs) + wid * 512;                                \
        gld_lds16(kSrc0 + (size_t)(kt0_) * 64, _lkw);                           \
        gld_lds16(kSrc0 + (size_t)((kt0_) + 32) * 64, _lkw + 2048);             \
    } while (0)
#define STAGE_V(kt0_)                                                           \
    do {                                                                        \
        u16* _lvw = lV + wid * 512;                                             \
        gld_lds16(vSrc0 + (kt0_), _lvw);                                        \
        gld_lds16(vSrc0 + ((size_t)32 << 11) + (kt0_), _lvw + 2048);            \
    } while (0)

    STAGE_K(0, 0);
    STAGE_V(0);
    asm volatile("s_waitcnt vmcnt(0)" ::: "memory");
    __builtin_amdgcn_s_barrier();

    for (int kt = 0; kt < nt; kt++) {
        const int kt0 = kt << 6;
        const int curofs = (kt & 1) ? 4096 : 0;

        if (kt + 1 < nt) {
            STAGE_K(curofs ^ 4096, kt0 + 64);
            asm volatile("s_waitcnt vmcnt(2)" ::: "memory");
            __builtin_amdgcn_s_barrier();
        } else if (nt > 1) {
            asm volatile("s_waitcnt vmcnt(0)" ::: "memory");
            __builtin_amdgcn_s_barrier();
        }
        const u16* lKc = smem + curofs;

        f32x4 s[2][2];
#pragma unroll
        for (int kg = 0; kg < 2; kg++)
#pragma unroll
            for (int qg = 0; qg < 2; qg++)
#pragma unroll
                for (int r = 0; r < 4; r++) s[kg][qg][r] = 0.f;
        __builtin_amdgcn_s_setprio(1);
#pragma unroll
        for (int kg = 0; kg < 2; kg++) {
            const int krow = (kw * 32 + kg * 16 + fr) * 64;
            bf16x8 kb0 = *(const bf16x8*)&lKc[krow + gk0];
            bf16x8 kb1 = *(const bf16x8*)&lKc[krow + gk1];
#pragma unroll
            for (int qg = 0; qg < 2; qg++) {
                s[kg][qg] = __builtin_amdgcn_mfma_f32_16x16x32_bf16(kb0, qa[qg][0], s[kg][qg], 0, 0, 0);
                s[kg][qg] = __builtin_amdgcn_mfma_f32_16x16x32_bf16(kb1, qa[qg][1], s[kg][qg], 0, 0, 0);
            }
        }
        __builtin_amdgcn_s_setprio(0);

        if (kt == nt - 1) {
#pragma unroll
            for (int kg = 0; kg < 2; kg++) {
                const int kg0 = kt0 + kw * 32 + kg * 16 + fq * 4;
#pragma unroll
                for (int qg = 0; qg < 2; qg++) {
                    const int qg0 = q0w + qg * 16 + fr;
#pragma unroll
                    for (int r = 0; r < 4; r++)
                        if (kg0 + r > qg0) s[kg][qg][r] = -200.f;
                }
            }
        }

        bf16x8 va[4];
#pragma unroll
        for (int dg = 0; dg < 4; dg++)
            va[dg] = *(const bf16x8*)&lV[(dg * 16 + fr) * 64 + gkv];

#pragma unroll
        for (int qg = 0; qg < 2; qg++) {
            unsigned pa = pk2(__builtin_amdgcn_exp2f(s[0][qg][0]), __builtin_amdgcn_exp2f(s[0][qg][1]));
            unsigned pb_ = pk2(__builtin_amdgcn_exp2f(s[0][qg][2]), __builtin_amdgcn_exp2f(s[0][qg][3]));
            unsigned pc = pk2(__builtin_amdgcn_exp2f(s[1][qg][0]), __builtin_amdgcn_exp2f(s[1][qg][1]));
            unsigned pd = pk2(__builtin_amdgcn_exp2f(s[1][qg][2]), __builtin_amdgcn_exp2f(s[1][qg][3]));
            asm("v_permlane32_swap_b32 %0, %1" : "+v"(pa), "+v"(pc));
            asm("v_permlane16_swap_b32 %0, %1" : "+v"(pa), "+v"(pc));
            asm("v_permlane32_swap_b32 %0, %1" : "+v"(pb_), "+v"(pd));
            asm("v_permlane16_swap_b32 %0, %1" : "+v"(pb_), "+v"(pd));
            union { unsigned u[4]; bf16x8 v; } pbu;
            pbu.u[0] = pa; pbu.u[1] = pb_; pbu.u[2] = pc; pbu.u[3] = pd;
            const bf16x8 pb = pbu.v;

            __builtin_amdgcn_s_setprio(1);
            lsum[qg] = __builtin_amdgcn_mfma_f32_16x16x32_bf16(vones, pb, lsum[qg], 0, 0, 0);
#pragma unroll
            for (int dg = 0; dg < 4; dg++)
                o[dg][qg] = __builtin_amdgcn_mfma_f32_16x16x32_bf16(va[dg], pb, o[dg][qg], 0, 0, 0);
            __builtin_amdgcn_s_setprio(0);
        }

        if (kt + 1 < nt) {
            __builtin_amdgcn_s_barrier();
            STAGE_V(kt0 + 64);
        }
    }
#undef STAGE_K
#undef STAGE_V

    __syncthreads();

    float* cmb = (float*)smem;
    float* slab = cmb + (size_t)qw * 2560 + lane * 40;
    if (kw == 1) {
#pragma unroll
        for (int dg = 0; dg < 4; dg++)
#pragma unroll
            for (int qg = 0; qg < 2; qg++)
                *(f32x4_a*)&slab[(dg * 2 + qg) * 4] = o[dg][qg];
#pragma unroll
        for (int qg = 0; qg < 2; qg++)
            *(f32x4_a*)&slab[32 + qg * 4] = lsum[qg];
    }
    __syncthreads();
    if (kw == 0) {
#pragma unroll
        for (int dg = 0; dg < 4; dg++)
#pragma unroll
            for (int qg = 0; qg < 2; qg++) {
                f32x4_a p = *(const f32x4_a*)&slab[(dg * 2 + qg) * 4];
#pragma unroll
                for (int r = 0; r < 4; r++) o[dg][qg][r] += p[r];
            }
#pragma unroll
        for (int qg = 0; qg < 2; qg++) {
            f32x4_a p = *(const f32x4_a*)&slab[32 + qg * 4];
            lsum[qg][0] += p[0];
        }

        const int bb = bh >> 4, hh = bh & 15;
#pragma unroll
        for (int qg = 0; qg < 2; qg++) {
            const float inv = 1.f / lsum[qg][0];
            u16* orow = O + ((size_t)(bb * 2048 + q0w + qg * 16 + fr)) * 1024 + hh * 64 + fq * 4;
#pragma unroll
            for (int dg = 0; dg < 4; dg++) {
                ushort4 h;
                h.x = f2bf(o[dg][qg][0] * inv);
                h.y = f2bf(o[dg][qg][1] * inv);
                h.z = f2bf(o[dg][qg][2] * inv);
                h.w = f2bf(o[dg][qg][3] * inv);
                *(ushort4*)&orow[dg * 16] = h;
            }
        }
    }
}

// ---------------------------------------------------------------------------
extern "C" void kernel_launch(void* const* d_in, const int* in_sizes, int n_in,
                              void* d_out, int out_size, void* d_ws, size_t ws_size,
                              hipStream_t stream) {
    const float* x      = (const float*)d_in[0];
    const float* w_qkv  = (const float*)d_in[1];
    const float* b_qkv  = (const float*)d_in[2];
    const float* w_proj = (const float*)d_in[3];
    const float* b_proj = (const float*)d_in[4];
    float* out = (float*)d_out;

    u16* ws = (u16*)d_ws;
    u16* wqkvT  = ws;                      // 3072*1024
    u16* wprojT = wqkvT + 3072 * 1024;     // 1024*1024
    u16* Qb     = wprojT + 1024 * 1024;    // 32*2048*64
    u16* Kb     = Qb + 32 * 2048 * 64;
    u16* Vtb    = Kb + 32 * 2048 * 64;     // transposed V [BH,64,2048]
    u16* xb     = Vtb + 32 * 2048 * 64;    // x as bf16; reused as attnO
    u16* attnO  = xb;                      // alias (xb dead after gemm1)

    prep_kernel<<<5120, 256, 0, stream>>>(x, xb, w_qkv, wqkvT);

    gemm_8ph<<<dim3(16, 32), 256, 0, stream>>>(xb, wqkvT, b_qkv, Qb, Kb, Vtb);

    attn_kernel<<<2048, 256, 0, stream>>>(Qb, Kb, Vtb, attnO, w_proj, wprojT);

    gemm_m97<64><<<dim3(16, 32), 256, 0, stream>>>(
        attnO, wprojT, b_proj, out, 4096, 1024, 1024);
}